// Round 7
// baseline (1257.427 us; speedup 1.0000x reference)
//
#include <hip/hip_runtime.h>
#include <hip/hip_bf16.h>
#include <math.h>

typedef long long ll;
typedef unsigned short ushort_t;
typedef __attribute__((ext_vector_type(8))) __bf16 bf16x8;
typedef __attribute__((ext_vector_type(4))) float f32x4;

// ---------------- helpers ----------------
__device__ __forceinline__ ushort_t f2bf(float f) {
    __hip_bfloat16 h = __float2bfloat16(f);
    return *reinterpret_cast<ushort_t*>(&h);
}
__device__ __forceinline__ float bf2f(ushort_t u) {
    return __uint_as_float(((unsigned)u) << 16);
}
// global->LDS DMA: lds dest wave-uniform; lane i deposits at dest + i*16
__device__ __forceinline__ void stage16(const void* g_lane, void* lds_uniform) {
    __builtin_amdgcn_global_load_lds(
        (const __attribute__((address_space(1))) unsigned int*)g_lane,
        (__attribute__((address_space(3))) unsigned int*)lds_uniform, 16, 0, 0);
}

// DPP reduce over the 16 lanes of each DPP-row (= lo16 group), VALU pipe only.
#define DPPMAX(v, ctrl) v = fmaxf(v, __uint_as_float((unsigned)__builtin_amdgcn_update_dpp( \
        0, (int)__float_as_uint(v), (ctrl), 0xF, 0xF, true)))
#define DPPADD(v, ctrl) v = v + __uint_as_float((unsigned)__builtin_amdgcn_update_dpp( \
        0, (int)__float_as_uint(v), (ctrl), 0xF, 0xF, true))
__device__ __forceinline__ float red_max16(float v) {
    DPPMAX(v, 0xB1); DPPMAX(v, 0x4E); DPPMAX(v, 0x141); DPPMAX(v, 0x140); return v;
}
__device__ __forceinline__ float red_sum16(float v) {
    DPPADD(v, 0xB1); DPPADD(v, 0x4E); DPPADD(v, 0x141); DPPADD(v, 0x140); return v;
}

// ---------------- bf16 MFMA GEMM (B^T form), TK=64, double-buffered ----------------
//   C[z][m,n] = sum_k A[z][m,k] * B[z][n,k];  z1 = z/Z2, z2 = z%Z2
#define TM 128
#define TN 128
#define TK 64

__global__ __launch_bounds__(256)
void gemm_bf16(const ushort_t* __restrict__ Ab, const ushort_t* __restrict__ Bb,
               void* __restrict__ Cb,
               int M, int N, int K,
               int a_rs, int b_rs, int c_rs, int Z2,
               ll a_bs1, ll a_bs2, ll b_bs1, ll b_bs2, ll c_bs1, ll c_bs2,
               int out_f32)
{
    const int m0 = blockIdx.y * TM;
    const int n0 = blockIdx.x * TN;
    const int z1 = blockIdx.z / Z2, z2 = blockIdx.z % Z2;

    const ushort_t* A = Ab + z1 * a_bs1 + z2 * a_bs2;
    const ushort_t* B = Bb + z1 * b_bs1 + z2 * b_bs2;

    __shared__ ushort_t As[2][TM][TK];
    __shared__ ushort_t Bs[2][TN][TK];

    const int tid  = threadIdx.x;
    const int w    = tid >> 6;
    const int l    = tid & 63;
    const int lo16 = l & 15;
    const int quad = l >> 4;
    const int wm0  = (w & 1) * 64;
    const int wn0  = (w >> 1) * 64;

    const int srow  = l >> 3;
    const int sunit = (l & 7) ^ srow;

    f32x4 acc[4][4];
    const f32x4 zero = {0.f, 0.f, 0.f, 0.f};
#pragma unroll
    for (int mi = 0; mi < 4; ++mi)
#pragma unroll
        for (int nj = 0; nj < 4; ++nj) acc[mi][nj] = zero;

    const int nIter = K / TK;

#pragma unroll
    for (int i = 0; i < 4; ++i) {
        const int rr = w * 32 + i * 8;
        stage16(A + (ll)(m0 + rr + srow) * a_rs + sunit * 8, &As[0][rr][0]);
        stage16(B + (ll)(n0 + rr + srow) * b_rs + sunit * 8, &Bs[0][rr][0]);
    }

    int buf = 0;
    for (int it = 0; it < nIter; ++it) {
        __syncthreads();
        if (it + 1 < nIter) {
            const int k0 = (it + 1) * TK;
            const int nb = buf ^ 1;
#pragma unroll
            for (int i = 0; i < 4; ++i) {
                const int rr = w * 32 + i * 8;
                stage16(A + (ll)(m0 + rr + srow) * a_rs + (k0 + sunit * 8), &As[nb][rr][0]);
                stage16(B + (ll)(n0 + rr + srow) * b_rs + (k0 + sunit * 8), &Bs[nb][rr][0]);
            }
        }
#pragma unroll
        for (int h = 0; h < 2; ++h) {
            const int phys = (h * 4 + quad) ^ (lo16 & 7);
            bf16x8 af[4], bfr[4];
#pragma unroll
            for (int mi = 0; mi < 4; ++mi)
                af[mi] = *(const bf16x8*)&As[buf][wm0 + mi * 16 + lo16][phys * 8];
#pragma unroll
            for (int nj = 0; nj < 4; ++nj)
                bfr[nj] = *(const bf16x8*)&Bs[buf][wn0 + nj * 16 + lo16][phys * 8];
#pragma unroll
            for (int mi = 0; mi < 4; ++mi)
#pragma unroll
                for (int nj = 0; nj < 4; ++nj)
                    acc[mi][nj] = __builtin_amdgcn_mfma_f32_16x16x32_bf16(
                        af[mi], bfr[nj], acc[mi][nj], 0, 0, 0);
        }
        buf ^= 1;
    }

    if (out_f32) {
        float* C = (float*)Cb + z1 * c_bs1 + z2 * c_bs2;
#pragma unroll
        for (int mi = 0; mi < 4; ++mi)
#pragma unroll
            for (int r = 0; r < 4; ++r) {
                const ll row = m0 + wm0 + mi * 16 + quad * 4 + r;
                float* cr = C + row * (ll)c_rs + (n0 + wn0 + lo16);
#pragma unroll
                for (int nj = 0; nj < 4; ++nj) cr[nj * 16] = acc[mi][nj][r];
            }
    } else {
        ushort_t* C = (ushort_t*)Cb + z1 * c_bs1 + z2 * c_bs2;
#pragma unroll
        for (int mi = 0; mi < 4; ++mi)
#pragma unroll
            for (int r = 0; r < 4; ++r) {
                const ll row = m0 + wm0 + mi * 16 + quad * 4 + r;
                ushort_t* cr = C + row * (ll)c_rs + (n0 + wn0 + lo16);
#pragma unroll
                for (int nj = 0; nj < 4; ++nj) cr[nj * 16] = f2bf(acc[mi][nj][r]);
            }
    }
}

// ---------------- fused flash-MLA attention (8-wave, shared-staging tile pairs) --------
// Grid (16,16,2), 512 thr. Waves 0-3 own q-tile 2jj, waves 4-7 own q-tile 2jj+1; the two
// tiles SHARE one Ks/Vs staging per stage (tile lengths differ by 2 stages only).
// Block bx runs task jj=15-bx then jj=bx: exactly 68 stages per block (uniform), all
// sweeps ascend from KV 0 (K stays L2-aligned). Staging split: waves 0-5 stage Ks,
// waves 6-7 stage Vs. LDS 53248 -> 2 blocks/CU = 16 waves/CU.
#define QP_RS 3072
#define XP_RS 1152

__global__ __launch_bounds__(512, 4)
void flash_mla(const ushort_t* __restrict__ QP,    // [2][2048][3072]: q_up | q_r
               const ushort_t* __restrict__ WukT,  // [16][512][128]
               const ushort_t* __restrict__ XP,    // [2][2048][1152]: cq | K(576) | pad
               const ushort_t* __restrict__ VT,    // [2][16][128][2048]
               float* __restrict__ out,            // [2][2048][2048]
               float scale)
{
    const int h  = blockIdx.y;
    const int b  = blockIdx.z;

    // build: Bw[64][16u]@0 (16384) | Q3[128][72]@16384 (18432)
    // main : Ks[32][72u]@0 (36864) | Vs[128][4u]@36864 (8192) | P[8][1024B]@45056 (8192)
    __shared__ __align__(16) char smem[53248];
    ushort_t* Ks = (ushort_t*)smem;
    ushort_t* Vs = (ushort_t*)(smem + 36864);
    ushort_t* Bw = (ushort_t*)smem;
    ushort_t* Q3 = (ushort_t*)(smem + 16384);

    const int tid  = threadIdx.x;
    const int w    = tid >> 6;       // 0..7
    const int g    = w >> 2;         // tile group: 0 -> qt=2jj, 1 -> qt=2jj+1
    const int wl   = w & 3;          // wave-in-group
    const int l    = tid & 63;
    const int lo16 = l & 15;
    const int quad = l >> 4;
    char* Pw = smem + 45056 + w * 1024;

#pragma unroll 1
    for (int task = 0; task < 2; ++task) {
        const int jj = task ? (int)blockIdx.x : 15 - (int)blockIdx.x;  // long task first
        const int qt = 2 * jj + g;
        const int t0 = qt * 64;
        const int nstBlk = 4 * jj + 4;            // block stage count (tile 2jj+1's need)
        const int myLast = 2 * qt + (wl >> 1);    // last stage with any unmasked col

        // all waves done with prior task's LDS before re-staging Bw
        __syncthreads();

        // ---- phase 1: build Q A-frags qa[0..17]; Bw/Q3 serve all 128 rows ----
        bf16x8 qa[18];

#pragma unroll
        for (int i = 0; i < 2; ++i) {          // Bw kc=0: 8 waves x 2 loads
            int p = w * 128 + i * 64 + l;
            int r = p >> 4, u = p & 15, ul = u ^ (r & 15);
            stage16(WukT + ((ll)h * 512 + r) * 128 + ul * 8,
                    (char*)Bw + (ll)(w * 128 + i * 64) * 16);
        }
        // q_up A-frags straight from QP (L2-hot; overlaps the Bw DMA above)
        bf16x8 ab[4];
#pragma unroll
        for (int kd = 0; kd < 4; ++kd)
            ab[kd] = *(const bf16x8*)(QP + (ll)(b * 2048 + t0 + 16 * wl + lo16) * QP_RS +
                                      h * 128 + kd * 32 + quad * 8);
        __syncthreads();

        for (int kc = 0; kc < 8; ++kc) {
#pragma unroll
            for (int nt = 0; nt < 4; ++nt) {
                f32x4 c = {0.f, 0.f, 0.f, 0.f};
#pragma unroll
                for (int kd = 0; kd < 4; ++kd) {
                    bf16x8 bb = *(const bf16x8*)(Bw + (nt * 16 + lo16) * 128 +
                                                 (((kd * 4 + quad) ^ lo16) & 15) * 8);
                    c = __builtin_amdgcn_mfma_f32_16x16x32_bf16(ab[kd], bb, c, 0, 0, 0);
                }
#pragma unroll
                for (int r = 0; r < 4; ++r)
                    Q3[(w * 16 + quad * 4 + r) * 72 + nt * 16 + lo16] = f2bf(c[r]);
            }
#pragma unroll
            for (int kd2 = 0; kd2 < 2; ++kd2)
                qa[kc * 2 + kd2] = *(const bf16x8*)(Q3 + (w * 16 + lo16) * 72 + kd2 * 32 + quad * 8);

            if (kc < 7) {
                __syncthreads();
#pragma unroll
                for (int i = 0; i < 2; ++i) {
                    int p = w * 128 + i * 64 + l;
                    int r = p >> 4, u = p & 15, ul = u ^ (r & 15);
                    stage16(WukT + ((ll)h * 512 + (kc + 1) * 64 + r) * 128 + ul * 8,
                            (char*)Bw + (ll)(w * 128 + i * 64) * 16);
                }
                __syncthreads();
            }
        }
        // rope tail (k-tiles 16,17) from QP cols 2048..3071
#pragma unroll
        for (int kt = 16; kt < 18; ++kt)
            qa[kt] = *(const bf16x8*)(QP + (ll)(b * 2048 + t0 + 16 * wl + lo16) * QP_RS +
                                      2048 + h * 64 + (kt - 16) * 32 + quad * 8);

        // ---- phase 2: shared K/V loop over [0, nstBlk) ----
        f32x4 oacc[8];
        const f32x4 zero = {0.f, 0.f, 0.f, 0.f};
#pragma unroll
        for (int dt = 0; dt < 8; ++dt) oacc[dt] = zero;
        float mrow[4], lrow[4];
#pragma unroll
        for (int r = 0; r < 4; ++r) { mrow[r] = -3.0e38f; lrow[r] = 0.f; }

        for (int st = 0; st < nstBlk; ++st) {
            const int s0 = st * 32;
            __syncthreads();
            // stage once for all 8 waves: waves 0-5 -> Ks (6 loads), waves 6-7 -> Vs (4)
            if (w < 6) {
#pragma unroll
                for (int i = 0; i < 6; ++i) {
                    int p = w * 384 + i * 64 + l;        // 0..2303
                    int r = p / 72, u = p % 72, ul = u ^ (r & 7);
                    stage16(XP + (ll)(b * 2048 + s0 + r) * XP_RS + 512 + ul * 8,
                            (char*)Ks + (ll)(w * 384 + i * 64) * 16);
                }
            } else {
#pragma unroll
                for (int i = 0; i < 4; ++i) {
                    int p = (w - 6) * 256 + i * 64 + l;  // 0..511
                    int r = p >> 2, u = p & 3, ul = u ^ (r & 3);
                    stage16(VT + ((ll)(b * 16 + h) * 128 + r) * 2048 + s0 + ul * 8,
                            (char*)Vs + (ll)((w - 6) * 256 + i * 64) * 16);
                }
            }
            __syncthreads();

            if (st > myLast) continue;   // fully-masked (or past this tile's range)

            // S = Q.K^T (fp32), 16x32 per wave
            f32x4 sc[2];
            sc[0] = zero; sc[1] = zero;
            __builtin_amdgcn_s_setprio(1);
#pragma unroll
            for (int kt = 0; kt < 18; ++kt)
#pragma unroll
                for (int nt = 0; nt < 2; ++nt) {
                    int phys = (kt * 4 + quad) ^ (lo16 & 7);
                    bf16x8 kb = *(const bf16x8*)(Ks + (nt * 16 + lo16) * 576 + phys * 8);
                    sc[nt] = __builtin_amdgcn_mfma_f32_16x16x32_bf16(qa[kt], kb, sc[nt], 0, 0, 0);
                }
            __builtin_amdgcn_s_setprio(0);

            // scale + causal mask (diagonal tiles st >= 2*qt)
            const int rbase = 16 * wl + quad * 4;    // row - t0
#pragma unroll
            for (int nt = 0; nt < 2; ++nt)
#pragma unroll
                for (int r = 0; r < 4; ++r) sc[nt][r] *= scale;
            if (st >= 2 * qt) {
#pragma unroll
                for (int nt = 0; nt < 2; ++nt)
#pragma unroll
                    for (int r = 0; r < 4; ++r)
                        if ((s0 + nt * 16 + lo16) > (t0 + rbase + r))
                            sc[nt][r] = -INFINITY;
            }

            // online softmax per row (DPP reduce over lo16 — VALU pipe, no LDS)
            float alpha[4];
#pragma unroll
            for (int r = 0; r < 4; ++r) {
                float tm = red_max16(fmaxf(sc[0][r], sc[1][r]));
                float mnew = fmaxf(mrow[r], tm);
                alpha[r] = __expf(mrow[r] - mnew);
                mrow[r] = mnew;
                sc[0][r] = __expf(sc[0][r] - mnew);
                sc[1][r] = __expf(sc[1][r] - mnew);
                float rs = red_sum16(sc[0][r] + sc[1][r]);
                lrow[r] = lrow[r] * alpha[r] + rs;
            }
#pragma unroll
            for (int dt = 0; dt < 8; ++dt)
#pragma unroll
                for (int r = 0; r < 4; ++r) oacc[dt][r] *= alpha[r];

            // P -> bf16 -> wave-private swizzled LDS (1KB/wave) -> A-frag
#pragma unroll
            for (int nt = 0; nt < 2; ++nt)
#pragma unroll
                for (int r = 0; r < 4; ++r) {
                    int row = quad * 4 + r;
                    int col = nt * 16 + lo16;
                    *(ushort_t*)(Pw + row * 64 + (((col >> 3) ^ (row & 3)) << 4) + (col & 7) * 2)
                        = f2bf(sc[nt][r]);
                }
            bf16x8 pf = *(const bf16x8*)(Pw + lo16 * 64 + (quad ^ (lo16 & 3)) * 16);

            // O += P.V
            __builtin_amdgcn_s_setprio(1);
#pragma unroll
            for (int dt = 0; dt < 8; ++dt) {
                int phys = quad ^ (lo16 & 3);
                bf16x8 vb = *(const bf16x8*)(Vs + (dt * 16 + lo16) * 32 + phys * 8);
                oacc[dt] = __builtin_amdgcn_mfma_f32_16x16x32_bf16(pf, vb, oacc[dt], 0, 0, 0);
            }
            __builtin_amdgcn_s_setprio(0);
        }

        // ---- epilogue ----
#pragma unroll
        for (int r = 0; r < 4; ++r) {
            const float inv = 1.0f / lrow[r];
            const ll row = (ll)(b * 2048 + t0 + 16 * wl + quad * 4 + r);
#pragma unroll
            for (int dt = 0; dt < 8; ++dt)
                out[row * 2048 + h * 128 + dt * 16 + lo16] = oacc[dt][r] * inv;
        }
    }
}

// ---------------- conversion / layout kernels ----------------
__global__ void cvt_f32_bf16(const float* __restrict__ in, ushort_t* __restrict__ out, ll n4)
{
    ll i = (ll)blockIdx.x * 256 + threadIdx.x;
    if (i >= n4) return;
    float4 v = *(const float4*)(in + i * 4);
    ushort4 u;
    u.x = f2bf(v.x); u.y = f2bf(v.y); u.z = f2bf(v.z); u.w = f2bf(v.w);
    *(ushort4*)(out + i * 4) = u;
}

// WB1 [1152][2048]: 0..511 W_dq | 512..1023 W_dkv | 1024..1087 W_kr | pad 0
__global__ void build_wb1(const float* __restrict__ Wdq, const float* __restrict__ Wdkv,
                          const float* __restrict__ Wkr, ushort_t* __restrict__ out)
{
    ll i4 = ((ll)blockIdx.x * 256 + threadIdx.x) * 4;
    if (i4 >= (ll)1152 * 2048) return;
    int row = (int)(i4 >> 11);
    int col = (int)(i4 & 2047);
    float4 v = make_float4(0.f, 0.f, 0.f, 0.f);
    if (row < 512)       v = *(const float4*)(Wdq + (ll)row * 2048 + col);
    else if (row < 1024) v = *(const float4*)(Wdkv + (ll)(row - 512) * 2048 + col);
    else if (row < 1088) v = *(const float4*)(Wkr + (ll)(row - 1024) * 2048 + col);
    ushort4 u;
    u.x = f2bf(v.x); u.y = f2bf(v.y); u.z = f2bf(v.z); u.w = f2bf(v.w);
    *(ushort4*)(out + i4) = u;
}

__global__ void transpose_f32_bf16(const float* __restrict__ in, ushort_t* __restrict__ out,
                                   int R, int C, ll in_bs, ll out_bs)
{
    __shared__ float tile[32][33];
    const float* I = in + (ll)blockIdx.z * in_bs;
    ushort_t*    O = out + (ll)blockIdx.z * out_bs;
    int r0 = blockIdx.y * 32, c0 = blockIdx.x * 32;
    int tx = threadIdx.x & 31, ty = threadIdx.x >> 5;
#pragma unroll
    for (int i = 0; i < 4; ++i)
        tile[ty + i * 8][tx] = I[(ll)(r0 + ty + i * 8) * C + (c0 + tx)];
    __syncthreads();
#pragma unroll
    for (int i = 0; i < 4; ++i)
        O[(ll)(c0 + ty + i * 8) * R + (r0 + tx)] = f2bf(tile[tx][ty + i * 8]);
}

// rope on XP cols [1024..1088) in place (bf16)
__global__ void rope_kr(ushort_t* __restrict__ XP, const float* __restrict__ cb,
                        const float* __restrict__ sb)
{
    int idx = blockIdx.x * 256 + threadIdx.x;   // 2*2048*32
    if (idx >= 2 * 2048 * 32) return;
    int j = idx & 31, t = (idx >> 5) & 2047, b = idx >> 16;
    float c = cb[t * 32 + j], s = sb[t * 32 + j];
    ushort_t* p = XP + ((ll)(b * 2048 + t)) * 1152 + 1024 + 2 * j;
    float re = bf2f(p[0]), im = bf2f(p[1]);
    p[0] = f2bf(re * c - im * s);
    p[1] = f2bf(re * s + im * c);
}

// rope on QP cols [2048..3072) in place (bf16)
__global__ void rope_qr_ip(ushort_t* __restrict__ QP, const float* __restrict__ cb,
                           const float* __restrict__ sb)
{
    int idx = blockIdx.x * 256 + threadIdx.x;   // 4096*512 pairs
    if (idx >= 4096 * 512) return;
    int pj = idx & 511, h = pj >> 5, j = pj & 31;
    int row = idx >> 9;
    int t = row & 2047;
    float c = cb[t * 32 + j], s = sb[t * 32 + j];
    ll base = (ll)row * 3072 + 2048 + h * 64 + 2 * j;
    float re = bf2f(QP[base]), im = bf2f(QP[base + 1]);
    QP[base]     = f2bf(re * c - im * s);
    QP[base + 1] = f2bf(re * s + im * c);
}

// ---------------- host ----------------
static inline void gemmb(hipStream_t st, const ushort_t* A, const ushort_t* B, void* C,
                         int M, int N, int K, int a_rs, int b_rs, int c_rs,
                         int nb, int Z2,
                         ll a_bs1, ll a_bs2, ll b_bs1, ll b_bs2, ll c_bs1, ll c_bs2,
                         int of32)
{
    dim3 g(N / TN, M / TM, nb);
    gemm_bf16<<<g, 256, 0, st>>>(A, B, C, M, N, K, a_rs, b_rs, c_rs, Z2,
                                 a_bs1, a_bs2, b_bs1, b_bs2, c_bs1, c_bs2, of32);
}

extern "C" void kernel_launch(void* const* d_in, const int* in_sizes, int n_in,
                              void* d_out, int out_size, void* d_ws, size_t ws_size,
                              hipStream_t stream)
{
    const float* x     = (const float*)d_in[0];
    const float* cosb  = (const float*)d_in[1];
    const float* sinb  = (const float*)d_in[2];
    const float* W_dq  = (const float*)d_in[3];
    const float* W_uq  = (const float*)d_in[4];
    const float* W_dkv = (const float*)d_in[5];
    const float* W_uk  = (const float*)d_in[6];
    const float* W_uv  = (const float*)d_in[7];
    const float* W_qr  = (const float*)d_in[8];
    const float* W_kr  = (const float*)d_in[9];
    const float* W_o   = (const float*)d_in[10];
    float* out = (float*)d_out;

    const float scale = 0.07216878364870323f; // 1/sqrt(128+64)

    // ---- workspace (bytes), total 90.7 MB ----
    char* base = (char*)d_ws;
    ushort_t* WB1     = (ushort_t*)(base + 0);         // [1152][2048]       4.72 MB
    ushort_t* WukT_b  = (ushort_t*)(base + 4718592);   // [16][512][128]     2.10
    ushort_t* WuvT_b  = (ushort_t*)(base + 6815744);   // [512][2048]        2.10
    ushort_t* WB2     = (ushort_t*)(base + 8912896);   // [3072][512]        3.15
    ushort_t* veffT_b = (ushort_t*)(base + 12058624);  // [16][128][512]     2.10
    ushort_t* Wo_b    = (ushort_t*)(base + 14155776);  // [2048][2048]       8.39
    ushort_t* xb      = (ushort_t*)(base + 22544384);  // [4096][2048]       16.78
    ushort_t* XP      = (ushort_t*)(base + 39321600);  // [4096][1152]       9.44
    ushort_t* VT_all  = (ushort_t*)(base + 48758784);  // [2][16][128][2048] 16.78
    ushort_t* QP      = (ushort_t*)(base + 65536000);  // [4096][3072]       25.17

    // ---- prep ----
    cvt_f32_bf16<<<8192, 256, 0, stream>>>(x, xb, 2097152);
    cvt_f32_bf16<<<4096, 256, 0, stream>>>(W_o, Wo_b, 1048576);
    build_wb1<<<2304, 256, 0, stream>>>(W_dq, W_dkv, W_kr, WB1);
    transpose_f32_bf16<<<dim3(16, 4, 16), 256, 0, stream>>>(W_uk, WukT_b, 128, 512, 65536, 65536);
    transpose_f32_bf16<<<dim3(16, 64, 1), 256, 0, stream>>>(W_uv, WuvT_b, 2048, 512, 0, 0);
    transpose_f32_bf16<<<dim3(64, 16, 1), 256, 0, stream>>>(W_uq, WB2, 512, 2048, 0, 0);
    cvt_f32_bf16<<<512, 256, 0, stream>>>(W_qr, WB2 + (ll)2048 * 512, 131072);

    // veffT[h][d][k] = sum_c Wo[h*128+d][c] * WuvT[k][c]
    gemmb(stream, Wo_b, WuvT_b, veffT_b, 128, 512, 2048, 2048, 2048, 512,
          16, 16, 0, 262144, 0, 0, 0, 65536, 0);

    // XP = xb . WB1^T  ->  [cq | c_kv | c_kr | pad]
    gemmb(stream, xb, WB1, XP, 4096, 1152, 2048, 2048, 2048, 1152,
          1, 1, 0, 0, 0, 0, 0, 0, 0);
    rope_kr<<<512, 256, 0, stream>>>(XP, cosb, sinb);

    // VT[b][h][d][s] = sum_k veffT[h][d][k] * c_kv[b][s][k]
    gemmb(stream, veffT_b, XP + 512, VT_all, 128, 2048, 512, 512, 1152, 2048,
          32, 16, 0, 65536, (ll)2048 * 1152, 0, (ll)16 * 262144, 262144, 0);

    // QP = cq . WB2^T  ->  [q_up | q_r]; rope q_r in place
    gemmb(stream, XP, WB2, QP, 4096, 3072, 512, 1152, 512, 3072,
          1, 1, 0, 0, 0, 0, 0, 0, 0);
    rope_qr_ip<<<8192, 256, 0, stream>>>(QP, cosb, sinb);

    // ---- fused attention: 512x512thr blocks, shared-staging tile pairs, 68 stages ----
    flash_mla<<<dim3(16, 16, 2), 512, 0, stream>>>(QP, WukT_b, XP, VT_all, out, scale);

    (void)in_sizes; (void)n_in; (void)out_size; (void)ws_size;
}

// Round 8
// 668.175 us; speedup vs baseline: 1.8819x; 1.8819x over previous
//
#include <hip/hip_runtime.h>
#include <hip/hip_bf16.h>
#include <math.h>

typedef long long ll;
typedef unsigned short ushort_t;
typedef __attribute__((ext_vector_type(8))) __bf16 bf16x8;
typedef __attribute__((ext_vector_type(4))) float f32x4;

// ---------------- helpers ----------------
__device__ __forceinline__ ushort_t f2bf(float f) {
    __hip_bfloat16 h = __float2bfloat16(f);
    return *reinterpret_cast<ushort_t*>(&h);
}
__device__ __forceinline__ float bf2f(ushort_t u) {
    return __uint_as_float(((unsigned)u) << 16);
}
// global->LDS DMA: lds dest wave-uniform; lane i deposits at dest + i*16
__device__ __forceinline__ void stage16(const void* g_lane, void* lds_uniform) {
    __builtin_amdgcn_global_load_lds(
        (const __attribute__((address_space(1))) unsigned int*)g_lane,
        (__attribute__((address_space(3))) unsigned int*)lds_uniform, 16, 0, 0);
}

// DPP reduce over the 16 lanes of each DPP-row (= lo16 group), VALU pipe only.
#define DPPMAX(v, ctrl) v = fmaxf(v, __uint_as_float((unsigned)__builtin_amdgcn_update_dpp( \
        0, (int)__float_as_uint(v), (ctrl), 0xF, 0xF, true)))
#define DPPADD(v, ctrl) v = v + __uint_as_float((unsigned)__builtin_amdgcn_update_dpp( \
        0, (int)__float_as_uint(v), (ctrl), 0xF, 0xF, true))
__device__ __forceinline__ float red_max16(float v) {
    DPPMAX(v, 0xB1); DPPMAX(v, 0x4E); DPPMAX(v, 0x141); DPPMAX(v, 0x140); return v;
}
__device__ __forceinline__ float red_sum16(float v) {
    DPPADD(v, 0xB1); DPPADD(v, 0x4E); DPPADD(v, 0x141); DPPADD(v, 0x140); return v;
}

// ---------------- bf16 MFMA GEMM (B^T form), TK=64, double-buffered ----------------
//   C[z][m,n] = sum_k A[z][m,k] * B[z][n,k];  z1 = z/Z2, z2 = z%Z2
#define TM 128
#define TN 128
#define TK 64

__global__ __launch_bounds__(256)
void gemm_bf16(const ushort_t* __restrict__ Ab, const ushort_t* __restrict__ Bb,
               void* __restrict__ Cb,
               int M, int N, int K,
               int a_rs, int b_rs, int c_rs, int Z2,
               ll a_bs1, ll a_bs2, ll b_bs1, ll b_bs2, ll c_bs1, ll c_bs2,
               int out_f32)
{
    const int m0 = blockIdx.y * TM;
    const int n0 = blockIdx.x * TN;
    const int z1 = blockIdx.z / Z2, z2 = blockIdx.z % Z2;

    const ushort_t* A = Ab + z1 * a_bs1 + z2 * a_bs2;
    const ushort_t* B = Bb + z1 * b_bs1 + z2 * b_bs2;

    __shared__ ushort_t As[2][TM][TK];
    __shared__ ushort_t Bs[2][TN][TK];

    const int tid  = threadIdx.x;
    const int w    = tid >> 6;
    const int l    = tid & 63;
    const int lo16 = l & 15;
    const int quad = l >> 4;
    const int wm0  = (w & 1) * 64;
    const int wn0  = (w >> 1) * 64;

    const int srow  = l >> 3;
    const int sunit = (l & 7) ^ srow;

    f32x4 acc[4][4];
    const f32x4 zero = {0.f, 0.f, 0.f, 0.f};
#pragma unroll
    for (int mi = 0; mi < 4; ++mi)
#pragma unroll
        for (int nj = 0; nj < 4; ++nj) acc[mi][nj] = zero;

    const int nIter = K / TK;

#pragma unroll
    for (int i = 0; i < 4; ++i) {
        const int rr = w * 32 + i * 8;
        stage16(A + (ll)(m0 + rr + srow) * a_rs + sunit * 8, &As[0][rr][0]);
        stage16(B + (ll)(n0 + rr + srow) * b_rs + sunit * 8, &Bs[0][rr][0]);
    }

    int buf = 0;
    for (int it = 0; it < nIter; ++it) {
        __syncthreads();
        if (it + 1 < nIter) {
            const int k0 = (it + 1) * TK;
            const int nb = buf ^ 1;
#pragma unroll
            for (int i = 0; i < 4; ++i) {
                const int rr = w * 32 + i * 8;
                stage16(A + (ll)(m0 + rr + srow) * a_rs + (k0 + sunit * 8), &As[nb][rr][0]);
                stage16(B + (ll)(n0 + rr + srow) * b_rs + (k0 + sunit * 8), &Bs[nb][rr][0]);
            }
        }
#pragma unroll
        for (int h = 0; h < 2; ++h) {
            const int phys = (h * 4 + quad) ^ (lo16 & 7);
            bf16x8 af[4], bfr[4];
#pragma unroll
            for (int mi = 0; mi < 4; ++mi)
                af[mi] = *(const bf16x8*)&As[buf][wm0 + mi * 16 + lo16][phys * 8];
#pragma unroll
            for (int nj = 0; nj < 4; ++nj)
                bfr[nj] = *(const bf16x8*)&Bs[buf][wn0 + nj * 16 + lo16][phys * 8];
#pragma unroll
            for (int mi = 0; mi < 4; ++mi)
#pragma unroll
                for (int nj = 0; nj < 4; ++nj)
                    acc[mi][nj] = __builtin_amdgcn_mfma_f32_16x16x32_bf16(
                        af[mi], bfr[nj], acc[mi][nj], 0, 0, 0);
        }
        buf ^= 1;
    }

    if (out_f32) {
        float* C = (float*)Cb + z1 * c_bs1 + z2 * c_bs2;
#pragma unroll
        for (int mi = 0; mi < 4; ++mi)
#pragma unroll
            for (int r = 0; r < 4; ++r) {
                const ll row = m0 + wm0 + mi * 16 + quad * 4 + r;
                float* cr = C + row * (ll)c_rs + (n0 + wn0 + lo16);
#pragma unroll
                for (int nj = 0; nj < 4; ++nj) cr[nj * 16] = acc[mi][nj][r];
            }
    } else {
        ushort_t* C = (ushort_t*)Cb + z1 * c_bs1 + z2 * c_bs2;
#pragma unroll
        for (int mi = 0; mi < 4; ++mi)
#pragma unroll
            for (int r = 0; r < 4; ++r) {
                const ll row = m0 + wm0 + mi * 16 + quad * 4 + r;
                ushort_t* cr = C + row * (ll)c_rs + (n0 + wn0 + lo16);
#pragma unroll
                for (int nj = 0; nj < 4; ++nj) cr[nj * 16] = f2bf(acc[mi][nj][r]);
            }
    }
}

// ---------------- fused flash-MLA attention (8-wave, shared-staging tile pairs) --------
// Grid (16,16,2), 512 thr. Waves 0-3 own q-tile 2jj, waves 4-7 own q-tile 2jj+1; the two
// tiles SHARE one Ks/Vs staging per stage. Block bx runs task jj=15-bx then jj=bx:
// exactly 68 stages per block (uniform), all sweeps ascend from KV 0 (K L2-aligned).
// Staging split: waves 0-5 stage Ks, waves 6-7 stage Vs. LDS 53248 -> 2 blocks/CU.
// __launch_bounds__(512,2): arg2 is min BLOCKS/CU (CUDA semantics, verified round 7 where
// (512,4) forced VGPR=64 => massive spills). (512,2) => 16 waves/CU => 128-VGPR cap.
#define QP_RS 3072
#define XP_RS 1152

__global__ __launch_bounds__(512, 2)
void flash_mla(const ushort_t* __restrict__ QP,    // [2][2048][3072]: q_up | q_r
               const ushort_t* __restrict__ WukT,  // [16][512][128]
               const ushort_t* __restrict__ XP,    // [2][2048][1152]: cq | K(576) | pad
               const ushort_t* __restrict__ VT,    // [2][16][128][2048]
               float* __restrict__ out,            // [2][2048][2048]
               float scale)
{
    const int h  = blockIdx.y;
    const int b  = blockIdx.z;

    // build: Bw[64][16u]@0 (16384) | Q3[128][72]@16384 (18432)
    // main : Ks[32][72u]@0 (36864) | Vs[128][4u]@36864 (8192) | P[8][1024B]@45056 (8192)
    __shared__ __align__(16) char smem[53248];
    ushort_t* Ks = (ushort_t*)smem;
    ushort_t* Vs = (ushort_t*)(smem + 36864);
    ushort_t* Bw = (ushort_t*)smem;
    ushort_t* Q3 = (ushort_t*)(smem + 16384);

    const int tid  = threadIdx.x;
    const int w    = tid >> 6;       // 0..7
    const int g    = w >> 2;         // tile group: 0 -> qt=2jj, 1 -> qt=2jj+1
    const int wl   = w & 3;          // wave-in-group
    const int l    = tid & 63;
    const int lo16 = l & 15;
    const int quad = l >> 4;
    char* Pw = smem + 45056 + w * 1024;

#pragma unroll 1
    for (int task = 0; task < 2; ++task) {
        const int jj = task ? (int)blockIdx.x : 15 - (int)blockIdx.x;  // long task first
        const int qt = 2 * jj + g;
        const int t0 = qt * 64;
        const int nstBlk = 4 * jj + 4;            // block stage count (tile 2jj+1's need)
        const int myLast = 2 * qt + (wl >> 1);    // last stage with any unmasked col

        // all waves done with prior task's LDS before re-staging Bw
        __syncthreads();

        // ---- phase 1: build Q A-frags qa[0..17]; Bw/Q3 serve all 128 rows ----
        bf16x8 qa[18];

#pragma unroll
        for (int i = 0; i < 2; ++i) {          // Bw kc=0: 8 waves x 2 loads
            int p = w * 128 + i * 64 + l;
            int r = p >> 4, u = p & 15, ul = u ^ (r & 15);
            stage16(WukT + ((ll)h * 512 + r) * 128 + ul * 8,
                    (char*)Bw + (ll)(w * 128 + i * 64) * 16);
        }
        // q_up A-frags straight from QP (L2-hot; overlaps the Bw DMA above)
        bf16x8 ab[4];
#pragma unroll
        for (int kd = 0; kd < 4; ++kd)
            ab[kd] = *(const bf16x8*)(QP + (ll)(b * 2048 + t0 + 16 * wl + lo16) * QP_RS +
                                      h * 128 + kd * 32 + quad * 8);
        __syncthreads();

        for (int kc = 0; kc < 8; ++kc) {
#pragma unroll
            for (int nt = 0; nt < 4; ++nt) {
                f32x4 c = {0.f, 0.f, 0.f, 0.f};
#pragma unroll
                for (int kd = 0; kd < 4; ++kd) {
                    bf16x8 bb = *(const bf16x8*)(Bw + (nt * 16 + lo16) * 128 +
                                                 (((kd * 4 + quad) ^ lo16) & 15) * 8);
                    c = __builtin_amdgcn_mfma_f32_16x16x32_bf16(ab[kd], bb, c, 0, 0, 0);
                }
#pragma unroll
                for (int r = 0; r < 4; ++r)
                    Q3[(w * 16 + quad * 4 + r) * 72 + nt * 16 + lo16] = f2bf(c[r]);
            }
#pragma unroll
            for (int kd2 = 0; kd2 < 2; ++kd2)
                qa[kc * 2 + kd2] = *(const bf16x8*)(Q3 + (w * 16 + lo16) * 72 + kd2 * 32 + quad * 8);

            if (kc < 7) {
                __syncthreads();
#pragma unroll
                for (int i = 0; i < 2; ++i) {
                    int p = w * 128 + i * 64 + l;
                    int r = p >> 4, u = p & 15, ul = u ^ (r & 15);
                    stage16(WukT + ((ll)h * 512 + (kc + 1) * 64 + r) * 128 + ul * 8,
                            (char*)Bw + (ll)(w * 128 + i * 64) * 16);
                }
                __syncthreads();
            }
        }
        // rope tail (k-tiles 16,17) from QP cols 2048..3071
#pragma unroll
        for (int kt = 16; kt < 18; ++kt)
            qa[kt] = *(const bf16x8*)(QP + (ll)(b * 2048 + t0 + 16 * wl + lo16) * QP_RS +
                                      2048 + h * 64 + (kt - 16) * 32 + quad * 8);

        // ---- phase 2: shared K/V loop over [0, nstBlk) ----
        f32x4 oacc[8];
        const f32x4 zero = {0.f, 0.f, 0.f, 0.f};
#pragma unroll
        for (int dt = 0; dt < 8; ++dt) oacc[dt] = zero;
        float mrow[4], lrow[4];
#pragma unroll
        for (int r = 0; r < 4; ++r) { mrow[r] = -3.0e38f; lrow[r] = 0.f; }

        for (int st = 0; st < nstBlk; ++st) {
            const int s0 = st * 32;
            __syncthreads();
            // stage once for all 8 waves: waves 0-5 -> Ks (6 loads), waves 6-7 -> Vs (4)
            if (w < 6) {
#pragma unroll
                for (int i = 0; i < 6; ++i) {
                    int p = w * 384 + i * 64 + l;        // 0..2303
                    int r = p / 72, u = p % 72, ul = u ^ (r & 7);
                    stage16(XP + (ll)(b * 2048 + s0 + r) * XP_RS + 512 + ul * 8,
                            (char*)Ks + (ll)(w * 384 + i * 64) * 16);
                }
            } else {
#pragma unroll
                for (int i = 0; i < 4; ++i) {
                    int p = (w - 6) * 256 + i * 64 + l;  // 0..511
                    int r = p >> 2, u = p & 3, ul = u ^ (r & 3);
                    stage16(VT + ((ll)(b * 16 + h) * 128 + r) * 2048 + s0 + ul * 8,
                            (char*)Vs + (ll)((w - 6) * 256 + i * 64) * 16);
                }
            }
            __syncthreads();

            if (st > myLast) continue;   // fully-masked (or past this tile's range)

            // S = Q.K^T (fp32), 16x32 per wave
            f32x4 sc[2];
            sc[0] = zero; sc[1] = zero;
            __builtin_amdgcn_s_setprio(1);
#pragma unroll
            for (int kt = 0; kt < 18; ++kt)
#pragma unroll
                for (int nt = 0; nt < 2; ++nt) {
                    int phys = (kt * 4 + quad) ^ (lo16 & 7);
                    bf16x8 kb = *(const bf16x8*)(Ks + (nt * 16 + lo16) * 576 + phys * 8);
                    sc[nt] = __builtin_amdgcn_mfma_f32_16x16x32_bf16(qa[kt], kb, sc[nt], 0, 0, 0);
                }
            __builtin_amdgcn_s_setprio(0);

            // scale + causal mask (diagonal tiles st >= 2*qt)
            const int rbase = 16 * wl + quad * 4;    // row - t0
#pragma unroll
            for (int nt = 0; nt < 2; ++nt)
#pragma unroll
                for (int r = 0; r < 4; ++r) sc[nt][r] *= scale;
            if (st >= 2 * qt) {
#pragma unroll
                for (int nt = 0; nt < 2; ++nt)
#pragma unroll
                    for (int r = 0; r < 4; ++r)
                        if ((s0 + nt * 16 + lo16) > (t0 + rbase + r))
                            sc[nt][r] = -INFINITY;
            }

            // online softmax per row (DPP reduce over lo16 — VALU pipe, no LDS)
            float alpha[4];
#pragma unroll
            for (int r = 0; r < 4; ++r) {
                float tm = red_max16(fmaxf(sc[0][r], sc[1][r]));
                float mnew = fmaxf(mrow[r], tm);
                alpha[r] = __expf(mrow[r] - mnew);
                mrow[r] = mnew;
                sc[0][r] = __expf(sc[0][r] - mnew);
                sc[1][r] = __expf(sc[1][r] - mnew);
                float rs = red_sum16(sc[0][r] + sc[1][r]);
                lrow[r] = lrow[r] * alpha[r] + rs;
            }
#pragma unroll
            for (int dt = 0; dt < 8; ++dt)
#pragma unroll
                for (int r = 0; r < 4; ++r) oacc[dt][r] *= alpha[r];

            // P -> bf16 -> wave-private swizzled LDS (1KB/wave) -> A-frag
#pragma unroll
            for (int nt = 0; nt < 2; ++nt)
#pragma unroll
                for (int r = 0; r < 4; ++r) {
                    int row = quad * 4 + r;
                    int col = nt * 16 + lo16;
                    *(ushort_t*)(Pw + row * 64 + (((col >> 3) ^ (row & 3)) << 4) + (col & 7) * 2)
                        = f2bf(sc[nt][r]);
                }
            bf16x8 pf = *(const bf16x8*)(Pw + lo16 * 64 + (quad ^ (lo16 & 3)) * 16);

            // O += P.V
            __builtin_amdgcn_s_setprio(1);
#pragma unroll
            for (int dt = 0; dt < 8; ++dt) {
                int phys = quad ^ (lo16 & 3);
                bf16x8 vb = *(const bf16x8*)(Vs + (dt * 16 + lo16) * 32 + phys * 8);
                oacc[dt] = __builtin_amdgcn_mfma_f32_16x16x32_bf16(pf, vb, oacc[dt], 0, 0, 0);
            }
            __builtin_amdgcn_s_setprio(0);
        }

        // ---- epilogue ----
#pragma unroll
        for (int r = 0; r < 4; ++r) {
            const float inv = 1.0f / lrow[r];
            const ll row = (ll)(b * 2048 + t0 + 16 * wl + quad * 4 + r);
#pragma unroll
            for (int dt = 0; dt < 8; ++dt)
                out[row * 2048 + h * 128 + dt * 16 + lo16] = oacc[dt][r] * inv;
        }
    }
}

// ---------------- conversion / layout kernels ----------------
__global__ void cvt_f32_bf16(const float* __restrict__ in, ushort_t* __restrict__ out, ll n4)
{
    ll i = (ll)blockIdx.x * 256 + threadIdx.x;
    if (i >= n4) return;
    float4 v = *(const float4*)(in + i * 4);
    ushort4 u;
    u.x = f2bf(v.x); u.y = f2bf(v.y); u.z = f2bf(v.z); u.w = f2bf(v.w);
    *(ushort4*)(out + i * 4) = u;
}

// WB1 [1152][2048]: 0..511 W_dq | 512..1023 W_dkv | 1024..1087 W_kr | pad 0
__global__ void build_wb1(const float* __restrict__ Wdq, const float* __restrict__ Wdkv,
                          const float* __restrict__ Wkr, ushort_t* __restrict__ out)
{
    ll i4 = ((ll)blockIdx.x * 256 + threadIdx.x) * 4;
    if (i4 >= (ll)1152 * 2048) return;
    int row = (int)(i4 >> 11);
    int col = (int)(i4 & 2047);
    float4 v = make_float4(0.f, 0.f, 0.f, 0.f);
    if (row < 512)       v = *(const float4*)(Wdq + (ll)row * 2048 + col);
    else if (row < 1024) v = *(const float4*)(Wdkv + (ll)(row - 512) * 2048 + col);
    else if (row < 1088) v = *(const float4*)(Wkr + (ll)(row - 1024) * 2048 + col);
    ushort4 u;
    u.x = f2bf(v.x); u.y = f2bf(v.y); u.z = f2bf(v.z); u.w = f2bf(v.w);
    *(ushort4*)(out + i4) = u;
}

__global__ void transpose_f32_bf16(const float* __restrict__ in, ushort_t* __restrict__ out,
                                   int R, int C, ll in_bs, ll out_bs)
{
    __shared__ float tile[32][33];
    const float* I = in + (ll)blockIdx.z * in_bs;
    ushort_t*    O = out + (ll)blockIdx.z * out_bs;
    int r0 = blockIdx.y * 32, c0 = blockIdx.x * 32;
    int tx = threadIdx.x & 31, ty = threadIdx.x >> 5;
#pragma unroll
    for (int i = 0; i < 4; ++i)
        tile[ty + i * 8][tx] = I[(ll)(r0 + ty + i * 8) * C + (c0 + tx)];
    __syncthreads();
#pragma unroll
    for (int i = 0; i < 4; ++i)
        O[(ll)(c0 + ty + i * 8) * R + (r0 + tx)] = f2bf(tile[tx][ty + i * 8]);
}

// rope on XP cols [1024..1088) in place (bf16)
__global__ void rope_kr(ushort_t* __restrict__ XP, const float* __restrict__ cb,
                        const float* __restrict__ sb)
{
    int idx = blockIdx.x * 256 + threadIdx.x;   // 2*2048*32
    if (idx >= 2 * 2048 * 32) return;
    int j = idx & 31, t = (idx >> 5) & 2047, b = idx >> 16;
    float c = cb[t * 32 + j], s = sb[t * 32 + j];
    ushort_t* p = XP + ((ll)(b * 2048 + t)) * 1152 + 1024 + 2 * j;
    float re = bf2f(p[0]), im = bf2f(p[1]);
    p[0] = f2bf(re * c - im * s);
    p[1] = f2bf(re * s + im * c);
}

// rope on QP cols [2048..3072) in place (bf16)
__global__ void rope_qr_ip(ushort_t* __restrict__ QP, const float* __restrict__ cb,
                           const float* __restrict__ sb)
{
    int idx = blockIdx.x * 256 + threadIdx.x;   // 4096*512 pairs
    if (idx >= 4096 * 512) return;
    int pj = idx & 511, h = pj >> 5, j = pj & 31;
    int row = idx >> 9;
    int t = row & 2047;
    float c = cb[t * 32 + j], s = sb[t * 32 + j];
    ll base = (ll)row * 3072 + 2048 + h * 64 + 2 * j;
    float re = bf2f(QP[base]), im = bf2f(QP[base + 1]);
    QP[base]     = f2bf(re * c - im * s);
    QP[base + 1] = f2bf(re * s + im * c);
}

// ---------------- host ----------------
static inline void gemmb(hipStream_t st, const ushort_t* A, const ushort_t* B, void* C,
                         int M, int N, int K, int a_rs, int b_rs, int c_rs,
                         int nb, int Z2,
                         ll a_bs1, ll a_bs2, ll b_bs1, ll b_bs2, ll c_bs1, ll c_bs2,
                         int of32)
{
    dim3 g(N / TN, M / TM, nb);
    gemm_bf16<<<g, 256, 0, st>>>(A, B, C, M, N, K, a_rs, b_rs, c_rs, Z2,
                                 a_bs1, a_bs2, b_bs1, b_bs2, c_bs1, c_bs2, of32);
}

extern "C" void kernel_launch(void* const* d_in, const int* in_sizes, int n_in,
                              void* d_out, int out_size, void* d_ws, size_t ws_size,
                              hipStream_t stream)
{
    const float* x     = (const float*)d_in[0];
    const float* cosb  = (const float*)d_in[1];
    const float* sinb  = (const float*)d_in[2];
    const float* W_dq  = (const float*)d_in[3];
    const float* W_uq  = (const float*)d_in[4];
    const float* W_dkv = (const float*)d_in[5];
    const float* W_uk  = (const float*)d_in[6];
    const float* W_uv  = (const float*)d_in[7];
    const float* W_qr  = (const float*)d_in[8];
    const float* W_kr  = (const float*)d_in[9];
    const float* W_o   = (const float*)d_in[10];
    float* out = (float*)d_out;

    const float scale = 0.07216878364870323f; // 1/sqrt(128+64)

    // ---- workspace (bytes), total 90.7 MB ----
    char* base = (char*)d_ws;
    ushort_t* WB1     = (ushort_t*)(base + 0);         // [1152][2048]       4.72 MB
    ushort_t* WukT_b  = (ushort_t*)(base + 4718592);   // [16][512][128]     2.10
    ushort_t* WuvT_b  = (ushort_t*)(base + 6815744);   // [512][2048]        2.10
    ushort_t* WB2     = (ushort_t*)(base + 8912896);   // [3072][512]        3.15
    ushort_t* veffT_b = (ushort_t*)(base + 12058624);  // [16][128][512]     2.10
    ushort_t* Wo_b    = (ushort_t*)(base + 14155776);  // [2048][2048]       8.39
    ushort_t* xb      = (ushort_t*)(base + 22544384);  // [4096][2048]       16.78
    ushort_t* XP      = (ushort_t*)(base + 39321600);  // [4096][1152]       9.44
    ushort_t* VT_all  = (ushort_t*)(base + 48758784);  // [2][16][128][2048] 16.78
    ushort_t* QP      = (ushort_t*)(base + 65536000);  // [4096][3072]       25.17

    // ---- prep ----
    cvt_f32_bf16<<<8192, 256, 0, stream>>>(x, xb, 2097152);
    cvt_f32_bf16<<<4096, 256, 0, stream>>>(W_o, Wo_b, 1048576);
    build_wb1<<<2304, 256, 0, stream>>>(W_dq, W_dkv, W_kr, WB1);
    transpose_f32_bf16<<<dim3(16, 4, 16), 256, 0, stream>>>(W_uk, WukT_b, 128, 512, 65536, 65536);
    transpose_f32_bf16<<<dim3(16, 64, 1), 256, 0, stream>>>(W_uv, WuvT_b, 2048, 512, 0, 0);
    transpose_f32_bf16<<<dim3(64, 16, 1), 256, 0, stream>>>(W_uq, WB2, 512, 2048, 0, 0);
    cvt_f32_bf16<<<512, 256, 0, stream>>>(W_qr, WB2 + (ll)2048 * 512, 131072);

    // veffT[h][d][k] = sum_c Wo[h*128+d][c] * WuvT[k][c]
    gemmb(stream, Wo_b, WuvT_b, veffT_b, 128, 512, 2048, 2048, 2048, 512,
          16, 16, 0, 262144, 0, 0, 0, 65536, 0);

    // XP = xb . WB1^T  ->  [cq | c_kv | c_kr | pad]
    gemmb(stream, xb, WB1, XP, 4096, 1152, 2048, 2048, 2048, 1152,
          1, 1, 0, 0, 0, 0, 0, 0, 0);
    rope_kr<<<512, 256, 0, stream>>>(XP, cosb, sinb);

    // VT[b][h][d][s] = sum_k veffT[h][d][k] * c_kv[b][s][k]
    gemmb(stream, veffT_b, XP + 512, VT_all, 128, 2048, 512, 512, 1152, 2048,
          32, 16, 0, 65536, (ll)2048 * 1152, 0, (ll)16 * 262144, 262144, 0);

    // QP = cq . WB2^T  ->  [q_up | q_r]; rope q_r in place
    gemmb(stream, XP, WB2, QP, 4096, 3072, 512, 1152, 512, 3072,
          1, 1, 0, 0, 0, 0, 0, 0, 0);
    rope_qr_ip<<<8192, 256, 0, stream>>>(QP, cosb, sinb);

    // ---- fused attention: 512x512thr blocks, shared-staging tile pairs, 68 stages ----
    flash_mla<<<dim3(16, 16, 2), 512, 0, stream>>>(QP, WukT_b, XP, VT_all, out, scale);

    (void)in_sizes; (void)n_in; (void)out_size; (void)ws_size;
}

// Round 10
// 440.177 us; speedup vs baseline: 2.8566x; 1.5180x over previous
//
#include <hip/hip_runtime.h>
#include <hip/hip_bf16.h>
#include <math.h>

typedef long long ll;
typedef unsigned short ushort_t;
typedef __attribute__((ext_vector_type(8))) __bf16 bf16x8;
typedef __attribute__((ext_vector_type(4))) float f32x4;

// ---------------- helpers ----------------
__device__ __forceinline__ ushort_t f2bf(float f) {
    __hip_bfloat16 h = __float2bfloat16(f);
    return *reinterpret_cast<ushort_t*>(&h);
}
__device__ __forceinline__ float bf2f(ushort_t u) {
    return __uint_as_float(((unsigned)u) << 16);
}
// global->LDS DMA: lds dest wave-uniform; lane i deposits at dest + i*16
__device__ __forceinline__ void stage16(const void* g_lane, void* lds_uniform) {
    __builtin_amdgcn_global_load_lds(
        (const __attribute__((address_space(1))) unsigned int*)g_lane,
        (__attribute__((address_space(3))) unsigned int*)lds_uniform, 16, 0, 0);
}

// DPP reduce over the 16 lanes of each DPP-row (= lo16 group), VALU pipe only.
#define DPPMAX(v, ctrl) v = fmaxf(v, __uint_as_float((unsigned)__builtin_amdgcn_update_dpp( \
        0, (int)__float_as_uint(v), (ctrl), 0xF, 0xF, true)))
#define DPPADD(v, ctrl) v = v + __uint_as_float((unsigned)__builtin_amdgcn_update_dpp( \
        0, (int)__float_as_uint(v), (ctrl), 0xF, 0xF, true))
__device__ __forceinline__ float red_max16(float v) {
    DPPMAX(v, 0xB1); DPPMAX(v, 0x4E); DPPMAX(v, 0x141); DPPMAX(v, 0x140); return v;
}
__device__ __forceinline__ float red_sum16(float v) {
    DPPADD(v, 0xB1); DPPADD(v, 0x4E); DPPADD(v, 0x141); DPPADD(v, 0x140); return v;
}

// ---------------- bf16 MFMA GEMM (B^T form), TK=64, double-buffered ----------------
//   C[z][m,n] = sum_k A[z][m,k] * B[z][n,k];  z1 = z/Z2, z2 = z%Z2
#define TM 128
#define TN 128
#define TK 64

__global__ __launch_bounds__(256)
void gemm_bf16(const ushort_t* __restrict__ Ab, const ushort_t* __restrict__ Bb,
               void* __restrict__ Cb,
               int M, int N, int K,
               int a_rs, int b_rs, int c_rs, int Z2,
               ll a_bs1, ll a_bs2, ll b_bs1, ll b_bs2, ll c_bs1, ll c_bs2,
               int out_f32)
{
    const int m0 = blockIdx.y * TM;
    const int n0 = blockIdx.x * TN;
    const int z1 = blockIdx.z / Z2, z2 = blockIdx.z % Z2;

    const ushort_t* A = Ab + z1 * a_bs1 + z2 * a_bs2;
    const ushort_t* B = Bb + z1 * b_bs1 + z2 * b_bs2;

    __shared__ ushort_t As[2][TM][TK];
    __shared__ ushort_t Bs[2][TN][TK];

    const int tid  = threadIdx.x;
    const int w    = tid >> 6;
    const int l    = tid & 63;
    const int lo16 = l & 15;
    const int quad = l >> 4;
    const int wm0  = (w & 1) * 64;
    const int wn0  = (w >> 1) * 64;

    const int srow  = l >> 3;
    const int sunit = (l & 7) ^ srow;

    f32x4 acc[4][4];
    const f32x4 zero = {0.f, 0.f, 0.f, 0.f};
#pragma unroll
    for (int mi = 0; mi < 4; ++mi)
#pragma unroll
        for (int nj = 0; nj < 4; ++nj) acc[mi][nj] = zero;

    const int nIter = K / TK;

#pragma unroll
    for (int i = 0; i < 4; ++i) {
        const int rr = w * 32 + i * 8;
        stage16(A + (ll)(m0 + rr + srow) * a_rs + sunit * 8, &As[0][rr][0]);
        stage16(B + (ll)(n0 + rr + srow) * b_rs + sunit * 8, &Bs[0][rr][0]);
    }

    int buf = 0;
    for (int it = 0; it < nIter; ++it) {
        __syncthreads();
        if (it + 1 < nIter) {
            const int k0 = (it + 1) * TK;
            const int nb = buf ^ 1;
#pragma unroll
            for (int i = 0; i < 4; ++i) {
                const int rr = w * 32 + i * 8;
                stage16(A + (ll)(m0 + rr + srow) * a_rs + (k0 + sunit * 8), &As[nb][rr][0]);
                stage16(B + (ll)(n0 + rr + srow) * b_rs + (k0 + sunit * 8), &Bs[nb][rr][0]);
            }
        }
#pragma unroll
        for (int h = 0; h < 2; ++h) {
            const int phys = (h * 4 + quad) ^ (lo16 & 7);
            bf16x8 af[4], bfr[4];
#pragma unroll
            for (int mi = 0; mi < 4; ++mi)
                af[mi] = *(const bf16x8*)&As[buf][wm0 + mi * 16 + lo16][phys * 8];
#pragma unroll
            for (int nj = 0; nj < 4; ++nj)
                bfr[nj] = *(const bf16x8*)&Bs[buf][wn0 + nj * 16 + lo16][phys * 8];
#pragma unroll
            for (int mi = 0; mi < 4; ++mi)
#pragma unroll
                for (int nj = 0; nj < 4; ++nj)
                    acc[mi][nj] = __builtin_amdgcn_mfma_f32_16x16x32_bf16(
                        af[mi], bfr[nj], acc[mi][nj], 0, 0, 0);
        }
        buf ^= 1;
    }

    if (out_f32) {
        float* C = (float*)Cb + z1 * c_bs1 + z2 * c_bs2;
#pragma unroll
        for (int mi = 0; mi < 4; ++mi)
#pragma unroll
            for (int r = 0; r < 4; ++r) {
                const ll row = m0 + wm0 + mi * 16 + quad * 4 + r;
                float* cr = C + row * (ll)c_rs + (n0 + wn0 + lo16);
#pragma unroll
                for (int nj = 0; nj < 4; ++nj) cr[nj * 16] = acc[mi][nj][r];
            }
    } else {
        ushort_t* C = (ushort_t*)Cb + z1 * c_bs1 + z2 * c_bs2;
#pragma unroll
        for (int mi = 0; mi < 4; ++mi)
#pragma unroll
            for (int r = 0; r < 4; ++r) {
                const ll row = m0 + wm0 + mi * 16 + quad * 4 + r;
                ushort_t* cr = C + row * (ll)c_rs + (n0 + wn0 + lo16);
#pragma unroll
                for (int nj = 0; nj < 4; ++nj) cr[nj * 16] = f2bf(acc[mi][nj][r]);
            }
    }
}

// ---------------- fused flash-MLA attention (8-wave, shared staging, K/V dbuf) --------
// Grid (8,16,2) = 256 blocks, 512 thr. Waves 0-3 own q-tile 2jj, waves 4-7 own q-tile
// 2jj+1, sharing one K/V staging. Block bx runs task jj=15-bx then jj=bx: uniform 68
// stages/block; all sweeps ascend from KV 0 (K L2-aligned). 1 block/CU (LDS 96KB) ->
// overlap from DOUBLE-BUFFERED staging (barrier; issue next-tile DMA; compute current).
// NOTE: LDS buffer selection via byte-offset arithmetic, NOT pointer arrays (an
// initializer of LDS pointers emits an unsupported addrspacecast on gfx950 — round 9).
#define QP_RS 3072
#define XP_RS 1152

__global__ __launch_bounds__(512)
void flash_mla(const ushort_t* __restrict__ QP,    // [2][2048][3072]: q_up | q_r
               const ushort_t* __restrict__ WukT,  // [16][512][128]
               const ushort_t* __restrict__ XP,    // [2][2048][1152]: cq | K(576) | pad
               const ushort_t* __restrict__ VT,    // [2][16][128][2048]
               float* __restrict__ out,            // [2][2048][2048]
               float scale)
{
    const int h  = blockIdx.y;
    const int b  = blockIdx.z;

    // main : Ks[2][32][72u]@0 (73728) | Vs[2][128][4u]@73728 (16384) | P[8][1KB]@90112 (8192)
    // build: Bw[64][16u]@0 (16384) | Q3[128][72]@16384 (18432)   (overlays Ks[0])
    __shared__ __align__(16) char smem[98304];
    ushort_t* Bw = (ushort_t*)smem;
    ushort_t* Q3 = (ushort_t*)(smem + 16384);

    const int tid  = threadIdx.x;
    const int w    = tid >> 6;       // 0..7
    const int g    = w >> 2;         // tile group: 0 -> qt=2jj, 1 -> qt=2jj+1
    const int wl   = w & 3;          // wave-in-group
    const int l    = tid & 63;
    const int lo16 = l & 15;
    const int quad = l >> 4;
    char* Pw = smem + 90112 + w * 1024;

#pragma unroll 1
    for (int task = 0; task < 2; ++task) {
        const int jj = task ? (int)blockIdx.x : 15 - (int)blockIdx.x;  // long task first
        const int qt = 2 * jj + g;
        const int t0 = qt * 64;
        const int nst = 4 * jj + 4;               // block stage count
        const int myLast = 2 * qt + (wl >> 1);    // last stage with any unmasked col

        // all waves done with prior task's LDS before re-staging Bw
        __syncthreads();

        // ---- phase 1: build Q A-frags qa[0..17]; Bw/Q3 serve all 128 rows ----
        bf16x8 qa[18];

#pragma unroll
        for (int i = 0; i < 2; ++i) {          // Bw kc=0: 8 waves x 2 loads
            int p = w * 128 + i * 64 + l;
            int r = p >> 4, u = p & 15, ul = u ^ (r & 15);
            stage16(WukT + ((ll)h * 512 + r) * 128 + ul * 8,
                    (char*)Bw + (ll)(w * 128 + i * 64) * 16);
        }
        // q_up A-frags straight from QP (L2-hot; overlaps the Bw DMA above)
        bf16x8 ab[4];
#pragma unroll
        for (int kd = 0; kd < 4; ++kd)
            ab[kd] = *(const bf16x8*)(QP + (ll)(b * 2048 + t0 + 16 * wl + lo16) * QP_RS +
                                      h * 128 + kd * 32 + quad * 8);
        __syncthreads();

        for (int kc = 0; kc < 8; ++kc) {
#pragma unroll
            for (int nt = 0; nt < 4; ++nt) {
                f32x4 c = {0.f, 0.f, 0.f, 0.f};
#pragma unroll
                for (int kd = 0; kd < 4; ++kd) {
                    bf16x8 bb = *(const bf16x8*)(Bw + (nt * 16 + lo16) * 128 +
                                                 (((kd * 4 + quad) ^ lo16) & 15) * 8);
                    c = __builtin_amdgcn_mfma_f32_16x16x32_bf16(ab[kd], bb, c, 0, 0, 0);
                }
#pragma unroll
                for (int r = 0; r < 4; ++r)
                    Q3[(w * 16 + quad * 4 + r) * 72 + nt * 16 + lo16] = f2bf(c[r]);
            }
#pragma unroll
            for (int kd2 = 0; kd2 < 2; ++kd2)
                qa[kc * 2 + kd2] = *(const bf16x8*)(Q3 + (w * 16 + lo16) * 72 + kd2 * 32 + quad * 8);

            if (kc < 7) {
                __syncthreads();
#pragma unroll
                for (int i = 0; i < 2; ++i) {
                    int p = w * 128 + i * 64 + l;
                    int r = p >> 4, u = p & 15, ul = u ^ (r & 15);
                    stage16(WukT + ((ll)h * 512 + (kc + 1) * 64 + r) * 128 + ul * 8,
                            (char*)Bw + (ll)(w * 128 + i * 64) * 16);
                }
                __syncthreads();
            }
        }
        // rope tail (k-tiles 16,17) from QP cols 2048..3071
#pragma unroll
        for (int kt = 16; kt < 18; ++kt)
            qa[kt] = *(const bf16x8*)(QP + (ll)(b * 2048 + t0 + 16 * wl + lo16) * QP_RS +
                                      2048 + h * 64 + (kt - 16) * 32 + quad * 8);

        // ---- phase 2: K/V loop, double-buffered staging ----
        f32x4 oacc[8];
        const f32x4 zero = {0.f, 0.f, 0.f, 0.f};
#pragma unroll
        for (int dt = 0; dt < 8; ++dt) oacc[dt] = zero;
        float mrow[4], lrow[4];
#pragma unroll
        for (int r = 0; r < 4; ++r) { mrow[r] = -3.0e38f; lrow[r] = 0.f; }

        __syncthreads();   // Q3 reads done before Ks[0] staging overwrites it

        // prologue: stage st=0 into buffer 0
        if (w < 6) {
#pragma unroll
            for (int i = 0; i < 6; ++i) {
                int p = w * 384 + i * 64 + l;        // 0..2303
                int r = p / 72, u = p % 72, ul = u ^ (r & 7);
                stage16(XP + (ll)(b * 2048 + r) * XP_RS + 512 + ul * 8,
                        smem + (ll)(w * 384 + i * 64) * 16);
            }
        } else {
#pragma unroll
            for (int i = 0; i < 4; ++i) {
                int p = (w - 6) * 256 + i * 64 + l;  // 0..511
                int r = p >> 2, u = p & 3, ul = u ^ (r & 3);
                stage16(VT + ((ll)(b * 16 + h) * 128 + r) * 2048 + ul * 8,
                        smem + 73728 + (ll)((w - 6) * 256 + i * 64) * 16);
            }
        }

        int buf = 0;
        for (int st = 0; st < nst; ++st) {
            // barrier drains this wave's DMA (compiler emits vmcnt(0)) and syncs all
            // waves: buf's tile is complete, buf^1's readers from st-1 are done.
            __syncthreads();

            if (st + 1 < nst) {
                const int s0n = (st + 1) * 32;
                const int nb = buf ^ 1;
                if (w < 6) {
                    char* ksn = smem + nb * 36864;
#pragma unroll
                    for (int i = 0; i < 6; ++i) {
                        int p = w * 384 + i * 64 + l;
                        int r = p / 72, u = p % 72, ul = u ^ (r & 7);
                        stage16(XP + (ll)(b * 2048 + s0n + r) * XP_RS + 512 + ul * 8,
                                ksn + (ll)(w * 384 + i * 64) * 16);
                    }
                } else {
                    char* vsn = smem + 73728 + nb * 8192;
#pragma unroll
                    for (int i = 0; i < 4; ++i) {
                        int p = (w - 6) * 256 + i * 64 + l;
                        int r = p >> 2, u = p & 3, ul = u ^ (r & 3);
                        stage16(VT + ((ll)(b * 16 + h) * 128 + r) * 2048 + s0n + ul * 8,
                                vsn + (ll)((w - 6) * 256 + i * 64) * 16);
                    }
                }
            }

            if (st <= myLast) {
                const int s0 = st * 32;
                const ushort_t* Ks = (const ushort_t*)(smem + buf * 36864);
                const ushort_t* Vs = (const ushort_t*)(smem + 73728 + buf * 8192);

                // S = Q.K^T (fp32), 16x32 per wave
                f32x4 sc[2];
                sc[0] = zero; sc[1] = zero;
                __builtin_amdgcn_s_setprio(1);
#pragma unroll
                for (int kt = 0; kt < 18; ++kt)
#pragma unroll
                    for (int nt = 0; nt < 2; ++nt) {
                        int phys = (kt * 4 + quad) ^ (lo16 & 7);
                        bf16x8 kb = *(const bf16x8*)(Ks + (nt * 16 + lo16) * 576 + phys * 8);
                        sc[nt] = __builtin_amdgcn_mfma_f32_16x16x32_bf16(qa[kt], kb, sc[nt], 0, 0, 0);
                    }
                __builtin_amdgcn_s_setprio(0);

                // scale + causal mask (diagonal tiles st >= 2*qt)
                const int rbase = 16 * wl + quad * 4;    // row - t0
#pragma unroll
                for (int nt = 0; nt < 2; ++nt)
#pragma unroll
                    for (int r = 0; r < 4; ++r) sc[nt][r] *= scale;
                if (st >= 2 * qt) {
#pragma unroll
                    for (int nt = 0; nt < 2; ++nt)
#pragma unroll
                        for (int r = 0; r < 4; ++r)
                            if ((s0 + nt * 16 + lo16) > (t0 + rbase + r))
                                sc[nt][r] = -INFINITY;
                }

                // online softmax per row (DPP reduce over lo16 — VALU pipe, no LDS)
                float alpha[4];
#pragma unroll
                for (int r = 0; r < 4; ++r) {
                    float tm = red_max16(fmaxf(sc[0][r], sc[1][r]));
                    float mnew = fmaxf(mrow[r], tm);
                    alpha[r] = __expf(mrow[r] - mnew);
                    mrow[r] = mnew;
                    sc[0][r] = __expf(sc[0][r] - mnew);
                    sc[1][r] = __expf(sc[1][r] - mnew);
                    float rs = red_sum16(sc[0][r] + sc[1][r]);
                    lrow[r] = lrow[r] * alpha[r] + rs;
                }
#pragma unroll
                for (int dt = 0; dt < 8; ++dt)
#pragma unroll
                    for (int r = 0; r < 4; ++r) oacc[dt][r] *= alpha[r];

                // P -> bf16 -> wave-private swizzled LDS (1KB/wave) -> A-frag
#pragma unroll
                for (int nt = 0; nt < 2; ++nt)
#pragma unroll
                    for (int r = 0; r < 4; ++r) {
                        int row = quad * 4 + r;
                        int col = nt * 16 + lo16;
                        *(ushort_t*)(Pw + row * 64 + (((col >> 3) ^ (row & 3)) << 4) + (col & 7) * 2)
                            = f2bf(sc[nt][r]);
                    }
                bf16x8 pf = *(const bf16x8*)(Pw + lo16 * 64 + (quad ^ (lo16 & 3)) * 16);

                // O += P.V
                __builtin_amdgcn_s_setprio(1);
#pragma unroll
                for (int dt = 0; dt < 8; ++dt) {
                    int phys = quad ^ (lo16 & 3);
                    bf16x8 vb = *(const bf16x8*)(Vs + (dt * 16 + lo16) * 32 + phys * 8);
                    oacc[dt] = __builtin_amdgcn_mfma_f32_16x16x32_bf16(pf, vb, oacc[dt], 0, 0, 0);
                }
                __builtin_amdgcn_s_setprio(0);
            }
            buf ^= 1;
        }

        // ---- epilogue ----
#pragma unroll
        for (int r = 0; r < 4; ++r) {
            const float inv = 1.0f / lrow[r];
            const ll row = (ll)(b * 2048 + t0 + 16 * wl + quad * 4 + r);
#pragma unroll
            for (int dt = 0; dt < 8; ++dt)
                out[row * 2048 + h * 128 + dt * 16 + lo16] = oacc[dt][r] * inv;
        }
    }
}

// ---------------- conversion / layout kernels ----------------
__global__ void cvt_f32_bf16(const float* __restrict__ in, ushort_t* __restrict__ out, ll n4)
{
    ll i = (ll)blockIdx.x * 256 + threadIdx.x;
    if (i >= n4) return;
    float4 v = *(const float4*)(in + i * 4);
    ushort4 u;
    u.x = f2bf(v.x); u.y = f2bf(v.y); u.z = f2bf(v.z); u.w = f2bf(v.w);
    *(ushort4*)(out + i * 4) = u;
}

// WB1 [1152][2048]: 0..511 W_dq | 512..1023 W_dkv | 1024..1087 W_kr | pad 0
__global__ void build_wb1(const float* __restrict__ Wdq, const float* __restrict__ Wdkv,
                          const float* __restrict__ Wkr, ushort_t* __restrict__ out)
{
    ll i4 = ((ll)blockIdx.x * 256 + threadIdx.x) * 4;
    if (i4 >= (ll)1152 * 2048) return;
    int row = (int)(i4 >> 11);
    int col = (int)(i4 & 2047);
    float4 v = make_float4(0.f, 0.f, 0.f, 0.f);
    if (row < 512)       v = *(const float4*)(Wdq + (ll)row * 2048 + col);
    else if (row < 1024) v = *(const float4*)(Wdkv + (ll)(row - 512) * 2048 + col);
    else if (row < 1088) v = *(const float4*)(Wkr + (ll)(row - 1024) * 2048 + col);
    ushort4 u;
    u.x = f2bf(v.x); u.y = f2bf(v.y); u.z = f2bf(v.z); u.w = f2bf(v.w);
    *(ushort4*)(out + i4) = u;
}

__global__ void transpose_f32_bf16(const float* __restrict__ in, ushort_t* __restrict__ out,
                                   int R, int C, ll in_bs, ll out_bs)
{
    __shared__ float tile[32][33];
    const float* I = in + (ll)blockIdx.z * in_bs;
    ushort_t*    O = out + (ll)blockIdx.z * out_bs;
    int r0 = blockIdx.y * 32, c0 = blockIdx.x * 32;
    int tx = threadIdx.x & 31, ty = threadIdx.x >> 5;
#pragma unroll
    for (int i = 0; i < 4; ++i)
        tile[ty + i * 8][tx] = I[(ll)(r0 + ty + i * 8) * C + (c0 + tx)];
    __syncthreads();
#pragma unroll
    for (int i = 0; i < 4; ++i)
        O[(ll)(c0 + ty + i * 8) * R + (r0 + tx)] = f2bf(tile[tx][ty + i * 8]);
}

// rope on XP cols [1024..1088) in place (bf16)
__global__ void rope_kr(ushort_t* __restrict__ XP, const float* __restrict__ cb,
                        const float* __restrict__ sb)
{
    int idx = blockIdx.x * 256 + threadIdx.x;   // 2*2048*32
    if (idx >= 2 * 2048 * 32) return;
    int j = idx & 31, t = (idx >> 5) & 2047, b = idx >> 16;
    float c = cb[t * 32 + j], s = sb[t * 32 + j];
    ushort_t* p = XP + ((ll)(b * 2048 + t)) * 1152 + 1024 + 2 * j;
    float re = bf2f(p[0]), im = bf2f(p[1]);
    p[0] = f2bf(re * c - im * s);
    p[1] = f2bf(re * s + im * c);
}

// rope on QP cols [2048..3072) in place (bf16)
__global__ void rope_qr_ip(ushort_t* __restrict__ QP, const float* __restrict__ cb,
                           const float* __restrict__ sb)
{
    int idx = blockIdx.x * 256 + threadIdx.x;   // 4096*512 pairs
    if (idx >= 4096 * 512) return;
    int pj = idx & 511, h = pj >> 5, j = pj & 31;
    int row = idx >> 9;
    int t = row & 2047;
    float c = cb[t * 32 + j], s = sb[t * 32 + j];
    ll base = (ll)row * 3072 + 2048 + h * 64 + 2 * j;
    float re = bf2f(QP[base]), im = bf2f(QP[base + 1]);
    QP[base]     = f2bf(re * c - im * s);
    QP[base + 1] = f2bf(re * s + im * c);
}

// ---------------- host ----------------
static inline void gemmb(hipStream_t st, const ushort_t* A, const ushort_t* B, void* C,
                         int M, int N, int K, int a_rs, int b_rs, int c_rs,
                         int nb, int Z2,
                         ll a_bs1, ll a_bs2, ll b_bs1, ll b_bs2, ll c_bs1, ll c_bs2,
                         int of32)
{
    dim3 g(N / TN, M / TM, nb);
    gemm_bf16<<<g, 256, 0, st>>>(A, B, C, M, N, K, a_rs, b_rs, c_rs, Z2,
                                 a_bs1, a_bs2, b_bs1, b_bs2, c_bs1, c_bs2, of32);
}

extern "C" void kernel_launch(void* const* d_in, const int* in_sizes, int n_in,
                              void* d_out, int out_size, void* d_ws, size_t ws_size,
                              hipStream_t stream)
{
    const float* x     = (const float*)d_in[0];
    const float* cosb  = (const float*)d_in[1];
    const float* sinb  = (const float*)d_in[2];
    const float* W_dq  = (const float*)d_in[3];
    const float* W_uq  = (const float*)d_in[4];
    const float* W_dkv = (const float*)d_in[5];
    const float* W_uk  = (const float*)d_in[6];
    const float* W_uv  = (const float*)d_in[7];
    const float* W_qr  = (const float*)d_in[8];
    const float* W_kr  = (const float*)d_in[9];
    const float* W_o   = (const float*)d_in[10];
    float* out = (float*)d_out;

    const float scale = 0.07216878364870323f; // 1/sqrt(128+64)

    // ---- workspace (bytes), total 90.7 MB ----
    char* base = (char*)d_ws;
    ushort_t* WB1     = (ushort_t*)(base + 0);         // [1152][2048]       4.72 MB
    ushort_t* WukT_b  = (ushort_t*)(base + 4718592);   // [16][512][128]     2.10
    ushort_t* WuvT_b  = (ushort_t*)(base + 6815744);   // [512][2048]        2.10
    ushort_t* WB2     = (ushort_t*)(base + 8912896);   // [3072][512]        3.15
    ushort_t* veffT_b = (ushort_t*)(base + 12058624);  // [16][128][512]     2.10
    ushort_t* Wo_b    = (ushort_t*)(base + 14155776);  // [2048][2048]       8.39
    ushort_t* xb      = (ushort_t*)(base + 22544384);  // [4096][2048]       16.78
    ushort_t* XP      = (ushort_t*)(base + 39321600);  // [4096][1152]       9.44
    ushort_t* VT_all  = (ushort_t*)(base + 48758784);  // [2][16][128][2048] 16.78
    ushort_t* QP      = (ushort_t*)(base + 65536000);  // [4096][3072]       25.17

    // ---- prep ----
    cvt_f32_bf16<<<8192, 256, 0, stream>>>(x, xb, 2097152);
    cvt_f32_bf16<<<4096, 256, 0, stream>>>(W_o, Wo_b, 1048576);
    build_wb1<<<2304, 256, 0, stream>>>(W_dq, W_dkv, W_kr, WB1);
    transpose_f32_bf16<<<dim3(16, 4, 16), 256, 0, stream>>>(W_uk, WukT_b, 128, 512, 65536, 65536);
    transpose_f32_bf16<<<dim3(16, 64, 1), 256, 0, stream>>>(W_uv, WuvT_b, 2048, 512, 0, 0);
    transpose_f32_bf16<<<dim3(64, 16, 1), 256, 0, stream>>>(W_uq, WB2, 512, 2048, 0, 0);
    cvt_f32_bf16<<<512, 256, 0, stream>>>(W_qr, WB2 + (ll)2048 * 512, 131072);

    // veffT[h][d][k] = sum_c Wo[h*128+d][c] * WuvT[k][c]
    gemmb(stream, Wo_b, WuvT_b, veffT_b, 128, 512, 2048, 2048, 2048, 512,
          16, 16, 0, 262144, 0, 0, 0, 65536, 0);

    // XP = xb . WB1^T  ->  [cq | c_kv | c_kr | pad]
    gemmb(stream, xb, WB1, XP, 4096, 1152, 2048, 2048, 2048, 1152,
          1, 1, 0, 0, 0, 0, 0, 0, 0);
    rope_kr<<<512, 256, 0, stream>>>(XP, cosb, sinb);

    // VT[b][h][d][s] = sum_k veffT[h][d][k] * c_kv[b][s][k]
    gemmb(stream, veffT_b, XP + 512, VT_all, 128, 2048, 512, 512, 1152, 2048,
          32, 16, 0, 65536, (ll)2048 * 1152, 0, (ll)16 * 262144, 262144, 0);

    // QP = cq . WB2^T  ->  [q_up | q_r]; rope q_r in place
    gemmb(stream, XP, WB2, QP, 4096, 3072, 512, 1152, 512, 3072,
          1, 1, 0, 0, 0, 0, 0, 0, 0);
    rope_qr_ip<<<8192, 256, 0, stream>>>(QP, cosb, sinb);

    // ---- fused attention: 256 blocks (bx in [0,8)), dbuf staging, 68 stages each ----
    flash_mla<<<dim3(8, 16, 2), 512, 0, stream>>>(QP, WukT_b, XP, VT_all, out, scale);

    (void)in_sizes; (void)n_in; (void)out_size; (void)ws_size;
}

// Round 11
// 412.597 us; speedup vs baseline: 3.0476x; 1.0668x over previous
//
#include <hip/hip_runtime.h>
#include <hip/hip_bf16.h>
#include <math.h>

typedef long long ll;
typedef unsigned short ushort_t;
typedef __attribute__((ext_vector_type(8))) __bf16 bf16x8;
typedef __attribute__((ext_vector_type(4))) float f32x4;

// ---------------- helpers ----------------
__device__ __forceinline__ ushort_t f2bf(float f) {
    __hip_bfloat16 h = __float2bfloat16(f);
    return *reinterpret_cast<ushort_t*>(&h);
}
__device__ __forceinline__ float bf2f(ushort_t u) {
    return __uint_as_float(((unsigned)u) << 16);
}
// global->LDS DMA: lds dest wave-uniform; lane i deposits at dest + i*16
__device__ __forceinline__ void stage16(const void* g_lane, void* lds_uniform) {
    __builtin_amdgcn_global_load_lds(
        (const __attribute__((address_space(1))) unsigned int*)g_lane,
        (__attribute__((address_space(3))) unsigned int*)lds_uniform, 16, 0, 0);
}

// DPP reduce over the 16 lanes of each DPP-row (= lo16 group), VALU pipe only.
#define DPPMAX(v, ctrl) v = fmaxf(v, __uint_as_float((unsigned)__builtin_amdgcn_update_dpp( \
        0, (int)__float_as_uint(v), (ctrl), 0xF, 0xF, true)))
#define DPPADD(v, ctrl) v = v + __uint_as_float((unsigned)__builtin_amdgcn_update_dpp( \
        0, (int)__float_as_uint(v), (ctrl), 0xF, 0xF, true))
__device__ __forceinline__ float red_max16(float v) {
    DPPMAX(v, 0xB1); DPPMAX(v, 0x4E); DPPMAX(v, 0x141); DPPMAX(v, 0x140); return v;
}
__device__ __forceinline__ float red_sum16(float v) {
    DPPADD(v, 0xB1); DPPADD(v, 0x4E); DPPADD(v, 0x141); DPPADD(v, 0x140); return v;
}

// ---------------- bf16 MFMA GEMM (B^T form), TK=64, double-buffered ----------------
//   C[z][m,n] = sum_k A[z][m,k] * B[z][n,k];  z1 = z/Z2, z2 = z%Z2
#define TM 128
#define TN 128
#define TK 64

__global__ __launch_bounds__(256)
void gemm_bf16(const ushort_t* __restrict__ Ab, const ushort_t* __restrict__ Bb,
               void* __restrict__ Cb,
               int M, int N, int K,
               int a_rs, int b_rs, int c_rs, int Z2,
               ll a_bs1, ll a_bs2, ll b_bs1, ll b_bs2, ll c_bs1, ll c_bs2,
               int out_f32)
{
    const int m0 = blockIdx.y * TM;
    const int n0 = blockIdx.x * TN;
    const int z1 = blockIdx.z / Z2, z2 = blockIdx.z % Z2;

    const ushort_t* A = Ab + z1 * a_bs1 + z2 * a_bs2;
    const ushort_t* B = Bb + z1 * b_bs1 + z2 * b_bs2;

    __shared__ ushort_t As[2][TM][TK];
    __shared__ ushort_t Bs[2][TN][TK];

    const int tid  = threadIdx.x;
    const int w    = tid >> 6;
    const int l    = tid & 63;
    const int lo16 = l & 15;
    const int quad = l >> 4;
    const int wm0  = (w & 1) * 64;
    const int wn0  = (w >> 1) * 64;

    const int srow  = l >> 3;
    const int sunit = (l & 7) ^ srow;

    f32x4 acc[4][4];
    const f32x4 zero = {0.f, 0.f, 0.f, 0.f};
#pragma unroll
    for (int mi = 0; mi < 4; ++mi)
#pragma unroll
        for (int nj = 0; nj < 4; ++nj) acc[mi][nj] = zero;

    const int nIter = K / TK;

#pragma unroll
    for (int i = 0; i < 4; ++i) {
        const int rr = w * 32 + i * 8;
        stage16(A + (ll)(m0 + rr + srow) * a_rs + sunit * 8, &As[0][rr][0]);
        stage16(B + (ll)(n0 + rr + srow) * b_rs + sunit * 8, &Bs[0][rr][0]);
    }

    int buf = 0;
    for (int it = 0; it < nIter; ++it) {
        __syncthreads();
        if (it + 1 < nIter) {
            const int k0 = (it + 1) * TK;
            const int nb = buf ^ 1;
#pragma unroll
            for (int i = 0; i < 4; ++i) {
                const int rr = w * 32 + i * 8;
                stage16(A + (ll)(m0 + rr + srow) * a_rs + (k0 + sunit * 8), &As[nb][rr][0]);
                stage16(B + (ll)(n0 + rr + srow) * b_rs + (k0 + sunit * 8), &Bs[nb][rr][0]);
            }
        }
#pragma unroll
        for (int h = 0; h < 2; ++h) {
            const int phys = (h * 4 + quad) ^ (lo16 & 7);
            bf16x8 af[4], bfr[4];
#pragma unroll
            for (int mi = 0; mi < 4; ++mi)
                af[mi] = *(const bf16x8*)&As[buf][wm0 + mi * 16 + lo16][phys * 8];
#pragma unroll
            for (int nj = 0; nj < 4; ++nj)
                bfr[nj] = *(const bf16x8*)&Bs[buf][wn0 + nj * 16 + lo16][phys * 8];
#pragma unroll
            for (int mi = 0; mi < 4; ++mi)
#pragma unroll
                for (int nj = 0; nj < 4; ++nj)
                    acc[mi][nj] = __builtin_amdgcn_mfma_f32_16x16x32_bf16(
                        af[mi], bfr[nj], acc[mi][nj], 0, 0, 0);
        }
        buf ^= 1;
    }

    if (out_f32) {
        float* C = (float*)Cb + z1 * c_bs1 + z2 * c_bs2;
#pragma unroll
        for (int mi = 0; mi < 4; ++mi)
#pragma unroll
            for (int r = 0; r < 4; ++r) {
                const ll row = m0 + wm0 + mi * 16 + quad * 4 + r;
                float* cr = C + row * (ll)c_rs + (n0 + wn0 + lo16);
#pragma unroll
                for (int nj = 0; nj < 4; ++nj) cr[nj * 16] = acc[mi][nj][r];
            }
    } else {
        ushort_t* C = (ushort_t*)Cb + z1 * c_bs1 + z2 * c_bs2;
#pragma unroll
        for (int mi = 0; mi < 4; ++mi)
#pragma unroll
            for (int r = 0; r < 4; ++r) {
                const ll row = m0 + wm0 + mi * 16 + quad * 4 + r;
                ushort_t* cr = C + row * (ll)c_rs + (n0 + wn0 + lo16);
#pragma unroll
                for (int nj = 0; nj < 4; ++nj) cr[nj * 16] = f2bf(acc[mi][nj][r]);
            }
    }
}

// ---------------- fused prep: all 7 dependency-free layout kernels in one launch -----
// ranges: [0,8192) x->xb | [8192,12288) Wo->Wo_b | [12288,14592) WB1 |
//         [14592,15104) W_qr cvt | [15104,16128) t(W_uk) | [16128,17152) t(W_uv) |
//         [17152,18176) t(W_uq).  Bodies identical to the former standalone kernels.
__global__ __launch_bounds__(256)
void prep_all(const float* __restrict__ x,    const float* __restrict__ Wo,
              const float* __restrict__ Wdq,  const float* __restrict__ Wdkv,
              const float* __restrict__ Wkr,  const float* __restrict__ Wuk,
              const float* __restrict__ Wuv,  const float* __restrict__ Wuq,
              const float* __restrict__ Wqr,
              ushort_t* __restrict__ xb,   ushort_t* __restrict__ Wo_b,
              ushort_t* __restrict__ WB1,  ushort_t* __restrict__ WukT,
              ushort_t* __restrict__ WuvT, ushort_t* __restrict__ WB2)
{
    __shared__ float tile[32][33];
    int bid = blockIdx.x;
    const int tid = threadIdx.x;

    if (bid < 8192) {                       // x -> xb  (8192*256*4 = 2097152 f4, exact)
        ll i = (ll)bid * 256 + tid;
        float4 v = *(const float4*)(x + i * 4);
        ushort4 u;
        u.x = f2bf(v.x); u.y = f2bf(v.y); u.z = f2bf(v.z); u.w = f2bf(v.w);
        *(ushort4*)(xb + i * 4) = u;
        return;
    }
    bid -= 8192;
    if (bid < 4096) {                       // Wo -> Wo_b (1048576 f4, exact)
        ll i = (ll)bid * 256 + tid;
        float4 v = *(const float4*)(Wo + i * 4);
        ushort4 u;
        u.x = f2bf(v.x); u.y = f2bf(v.y); u.z = f2bf(v.z); u.w = f2bf(v.w);
        *(ushort4*)(Wo_b + i * 4) = u;
        return;
    }
    bid -= 4096;
    if (bid < 2304) {                       // WB1 (2304*256*4 = 1152*2048, exact)
        ll i4 = ((ll)bid * 256 + tid) * 4;
        int row = (int)(i4 >> 11);
        int col = (int)(i4 & 2047);
        float4 v = make_float4(0.f, 0.f, 0.f, 0.f);
        if (row < 512)       v = *(const float4*)(Wdq + (ll)row * 2048 + col);
        else if (row < 1024) v = *(const float4*)(Wdkv + (ll)(row - 512) * 2048 + col);
        else if (row < 1088) v = *(const float4*)(Wkr + (ll)(row - 1024) * 2048 + col);
        ushort4 u;
        u.x = f2bf(v.x); u.y = f2bf(v.y); u.z = f2bf(v.z); u.w = f2bf(v.w);
        *(ushort4*)(WB1 + i4) = u;
        return;
    }
    bid -= 2304;
    if (bid < 512) {                        // W_qr -> WB2 + 2048*512 (131072 f4, exact)
        ll i = (ll)bid * 256 + tid;
        float4 v = *(const float4*)(Wqr + i * 4);
        ushort4 u;
        u.x = f2bf(v.x); u.y = f2bf(v.y); u.z = f2bf(v.z); u.w = f2bf(v.w);
        *(ushort4*)(WB2 + (ll)2048 * 512 + i * 4) = u;
        return;
    }
    bid -= 512;

    // transposes (f32 in -> bf16 out^T). grid.x = C/32, grid.y = R/32 decode.
    const float* I; ushort_t* O; int R, C, r0, c0;
    if (bid < 1024) {                       // W_uk [16 batches] 128x512 -> 512x128
        int bx = bid & 15, by = (bid >> 4) & 3, bz = bid >> 6;
        I = Wuk + (ll)bz * 65536; O = WukT + (ll)bz * 65536;
        R = 128; C = 512; r0 = by * 32; c0 = bx * 32;
    } else if (bid < 2048) {                // W_uv 2048x512 -> WuvT 512x2048
        int b2 = bid - 1024;
        I = Wuv; O = WuvT; R = 2048; C = 512;
        r0 = (b2 >> 4) * 32; c0 = (b2 & 15) * 32;
    } else {                                // W_uq 512x2048 -> WB2 2048x512
        int b2 = bid - 2048;
        I = Wuq; O = WB2; R = 512; C = 2048;
        r0 = (b2 >> 6) * 32; c0 = (b2 & 63) * 32;
    }
    int tx = tid & 31, ty = tid >> 5;
#pragma unroll
    for (int i = 0; i < 4; ++i)
        tile[ty + i * 8][tx] = I[(ll)(r0 + ty + i * 8) * C + (c0 + tx)];
    __syncthreads();
#pragma unroll
    for (int i = 0; i < 4; ++i)
        O[(ll)(c0 + ty + i * 8) * R + (r0 + tx)] = f2bf(tile[tx][ty + i * 8]);
}

// ---------------- veff split-K reduce: veffT = bf16(sum of 4 f32 partials) ----------
__global__ __launch_bounds__(256)
void reduce_veff(const float* __restrict__ s, ushort_t* __restrict__ out)
{
    ll i = ((ll)blockIdx.x * 256 + threadIdx.x) * 4;   // 1024 blocks * 1024B = 1048576 f32
    float4 a = *(const float4*)(s + i);
    float4 b = *(const float4*)(s + 1048576 + i);
    float4 c = *(const float4*)(s + 2097152 + i);
    float4 d = *(const float4*)(s + 3145728 + i);
    ushort4 u;
    u.x = f2bf(a.x + b.x + c.x + d.x);
    u.y = f2bf(a.y + b.y + c.y + d.y);
    u.z = f2bf(a.z + b.z + c.z + d.z);
    u.w = f2bf(a.w + b.w + c.w + d.w);
    *(ushort4*)(out + i) = u;
}

// ---------------- fused flash-MLA attention (8-wave, shared staging, K/V dbuf) --------
// Grid (8,16,2) = 256 blocks, 512 thr. Waves 0-3 own q-tile 2jj, waves 4-7 own q-tile
// 2jj+1, sharing one K/V staging. Block bx runs task jj=15-bx then jj=bx: uniform 68
// stages/block; all sweeps ascend from KV 0 (K L2-aligned). 1 block/CU (LDS 96KB) ->
// overlap from DOUBLE-BUFFERED staging (barrier; issue next-tile DMA; compute current).
// Round-11 delta: the Q-build's Bw staging is also double-buffered (Bw lives in the
// Ks[1] region, 2x16KB at 36864/53248) -> 9 barriers per build instead of 17, and the
// WukT DMA overlaps the build MFMAs. LDS buffer selection via byte-offset arithmetic,
// NOT pointer arrays (aggregate LDS-pointer init emits unsupported addrspacecast).
#define QP_RS 3072
#define XP_RS 1152

__global__ __launch_bounds__(512)
void flash_mla(const ushort_t* __restrict__ QP,    // [2][2048][3072]: q_up | q_r
               const ushort_t* __restrict__ WukT,  // [16][512][128]
               const ushort_t* __restrict__ XP,    // [2][2048][1152]: cq | K(576) | pad
               const ushort_t* __restrict__ VT,    // [2][16][128][2048]
               float* __restrict__ out,            // [2][2048][2048]
               float scale)
{
    const int h  = blockIdx.y;
    const int b  = blockIdx.z;

    // main : Ks[2][32][72u]@0 (73728) | Vs[2][128][4u]@73728 (16384) | P[8][1KB]@90112 (8192)
    // build: Q3[128][72]@16384 (18432) | Bw[2][64][16u]@36864 (32768, in Ks[1] region)
    __shared__ __align__(16) char smem[98304];
    ushort_t* Q3 = (ushort_t*)(smem + 16384);

    const int tid  = threadIdx.x;
    const int w    = tid >> 6;       // 0..7
    const int g    = w >> 2;         // tile group: 0 -> qt=2jj, 1 -> qt=2jj+1
    const int wl   = w & 3;          // wave-in-group
    const int l    = tid & 63;
    const int lo16 = l & 15;
    const int quad = l >> 4;
    char* Pw = smem + 90112 + w * 1024;

#pragma unroll 1
    for (int task = 0; task < 2; ++task) {
        const int jj = task ? (int)blockIdx.x : 15 - (int)blockIdx.x;  // long task first
        const int qt = 2 * jj + g;
        const int t0 = qt * 64;
        const int nst = 4 * jj + 4;               // block stage count
        const int myLast = 2 * qt + (wl >> 1);    // last stage with any unmasked col

        // all waves done with prior task's LDS before re-staging Bw
        __syncthreads();

        // ---- phase 1: build Q A-frags qa[0..17]; Bw double-buffered ----
        bf16x8 qa[18];

#pragma unroll
        for (int i = 0; i < 2; ++i) {          // Bw buf0 <- kc=0
            int p = w * 128 + i * 64 + l;
            int r = p >> 4, u = p & 15, ul = u ^ (r & 15);
            stage16(WukT + ((ll)h * 512 + r) * 128 + ul * 8,
                    smem + 36864 + (ll)(w * 128 + i * 64) * 16);
        }
        // q_up A-frags straight from QP (L2-hot; overlaps the Bw DMA above)
        bf16x8 ab[4];
#pragma unroll
        for (int kd = 0; kd < 4; ++kd)
            ab[kd] = *(const bf16x8*)(QP + (ll)(b * 2048 + t0 + 16 * wl + lo16) * QP_RS +
                                      h * 128 + kd * 32 + quad * 8);
        __syncthreads();   // Bw buf0 complete (vmcnt drain at barrier)

        int bwb = 0;
        for (int kc = 0; kc < 8; ++kc) {
            if (kc < 7) {                      // issue next Bw while computing current
                char* bwn = smem + 36864 + (ll)(bwb ^ 1) * 16384;
#pragma unroll
                for (int i = 0; i < 2; ++i) {
                    int p = w * 128 + i * 64 + l;
                    int r = p >> 4, u = p & 15, ul = u ^ (r & 15);
                    stage16(WukT + ((ll)h * 512 + (kc + 1) * 64 + r) * 128 + ul * 8,
                            bwn + (ll)(w * 128 + i * 64) * 16);
                }
            }
            const ushort_t* BwC = (const ushort_t*)(smem + 36864 + (ll)bwb * 16384);
#pragma unroll
            for (int nt = 0; nt < 4; ++nt) {
                f32x4 c = {0.f, 0.f, 0.f, 0.f};
#pragma unroll
                for (int kd = 0; kd < 4; ++kd) {
                    bf16x8 bb = *(const bf16x8*)(BwC + (nt * 16 + lo16) * 128 +
                                                 (((kd * 4 + quad) ^ lo16) & 15) * 8);
                    c = __builtin_amdgcn_mfma_f32_16x16x32_bf16(ab[kd], bb, c, 0, 0, 0);
                }
#pragma unroll
                for (int r = 0; r < 4; ++r)
                    Q3[(w * 16 + quad * 4 + r) * 72 + nt * 16 + lo16] = f2bf(c[r]);
            }
            // Q3 rows w*16..w*16+15 are wave-private: no barrier needed before re-read
#pragma unroll
            for (int kd2 = 0; kd2 < 2; ++kd2)
                qa[kc * 2 + kd2] = *(const bf16x8*)(Q3 + (w * 16 + lo16) * 72 + kd2 * 32 + quad * 8);

            __syncthreads();   // next Bw complete; prior Bw readers done
            bwb ^= 1;
        }
        // rope tail (k-tiles 16,17) from QP cols 2048..3071
#pragma unroll
        for (int kt = 16; kt < 18; ++kt)
            qa[kt] = *(const bf16x8*)(QP + (ll)(b * 2048 + t0 + 16 * wl + lo16) * QP_RS +
                                      2048 + h * 64 + (kt - 16) * 32 + quad * 8);

        // ---- phase 2: K/V loop, double-buffered staging ----
        // (kc=7's trailing barrier separates Q3 reads from the Ks[0] staging below)
        f32x4 oacc[8];
        const f32x4 zero = {0.f, 0.f, 0.f, 0.f};
#pragma unroll
        for (int dt = 0; dt < 8; ++dt) oacc[dt] = zero;
        float mrow[4], lrow[4];
#pragma unroll
        for (int r = 0; r < 4; ++r) { mrow[r] = -3.0e38f; lrow[r] = 0.f; }

        // prologue: stage st=0 into buffer 0
        if (w < 6) {
#pragma unroll
            for (int i = 0; i < 6; ++i) {
                int p = w * 384 + i * 64 + l;        // 0..2303
                int r = p / 72, u = p % 72, ul = u ^ (r & 7);
                stage16(XP + (ll)(b * 2048 + r) * XP_RS + 512 + ul * 8,
                        smem + (ll)(w * 384 + i * 64) * 16);
            }
        } else {
#pragma unroll
            for (int i = 0; i < 4; ++i) {
                int p = (w - 6) * 256 + i * 64 + l;  // 0..511
                int r = p >> 2, u = p & 3, ul = u ^ (r & 3);
                stage16(VT + ((ll)(b * 16 + h) * 128 + r) * 2048 + ul * 8,
                        smem + 73728 + (ll)((w - 6) * 256 + i * 64) * 16);
            }
        }

        int buf = 0;
        for (int st = 0; st < nst; ++st) {
            // barrier drains this wave's DMA (compiler emits vmcnt(0)) and syncs all
            // waves: buf's tile is complete, buf^1's readers from st-1 are done.
            __syncthreads();

            if (st + 1 < nst) {
                const int s0n = (st + 1) * 32;
                const int nb = buf ^ 1;
                if (w < 6) {
                    char* ksn = smem + nb * 36864;
#pragma unroll
                    for (int i = 0; i < 6; ++i) {
                        int p = w * 384 + i * 64 + l;
                        int r = p / 72, u = p % 72, ul = u ^ (r & 7);
                        stage16(XP + (ll)(b * 2048 + s0n + r) * XP_RS + 512 + ul * 8,
                                ksn + (ll)(w * 384 + i * 64) * 16);
                    }
                } else {
                    char* vsn = smem + 73728 + nb * 8192;
#pragma unroll
                    for (int i = 0; i < 4; ++i) {
                        int p = (w - 6) * 256 + i * 64 + l;
                        int r = p >> 2, u = p & 3, ul = u ^ (r & 3);
                        stage16(VT + ((ll)(b * 16 + h) * 128 + r) * 2048 + s0n + ul * 8,
                                vsn + (ll)((w - 6) * 256 + i * 64) * 16);
                    }
                }
            }

            if (st <= myLast) {
                const int s0 = st * 32;
                const ushort_t* Ks = (const ushort_t*)(smem + buf * 36864);
                const ushort_t* Vs = (const ushort_t*)(smem + 73728 + buf * 8192);

                // S = Q.K^T (fp32), 16x32 per wave
                f32x4 sc[2];
                sc[0] = zero; sc[1] = zero;
                __builtin_amdgcn_s_setprio(1);
#pragma unroll
                for (int kt = 0; kt < 18; ++kt)
#pragma unroll
                    for (int nt = 0; nt < 2; ++nt) {
                        int phys = (kt * 4 + quad) ^ (lo16 & 7);
                        bf16x8 kb = *(const bf16x8*)(Ks + (nt * 16 + lo16) * 576 + phys * 8);
                        sc[nt] = __builtin_amdgcn_mfma_f32_16x16x32_bf16(qa[kt], kb, sc[nt], 0, 0, 0);
                    }
                __builtin_amdgcn_s_setprio(0);

                // scale + causal mask (diagonal tiles st >= 2*qt)
                const int rbase = 16 * wl + quad * 4;    // row - t0
#pragma unroll
                for (int nt = 0; nt < 2; ++nt)
#pragma unroll
                    for (int r = 0; r < 4; ++r) sc[nt][r] *= scale;
                if (st >= 2 * qt) {
#pragma unroll
                    for (int nt = 0; nt < 2; ++nt)
#pragma unroll
                        for (int r = 0; r < 4; ++r)
                            if ((s0 + nt * 16 + lo16) > (t0 + rbase + r))
                                sc[nt][r] = -INFINITY;
                }

                // online softmax per row (DPP reduce over lo16 — VALU pipe, no LDS)
                float alpha[4];
#pragma unroll
                for (int r = 0; r < 4; ++r) {
                    float tm = red_max16(fmaxf(sc[0][r], sc[1][r]));
                    float mnew = fmaxf(mrow[r], tm);
                    alpha[r] = __expf(mrow[r] - mnew);
                    mrow[r] = mnew;
                    sc[0][r] = __expf(sc[0][r] - mnew);
                    sc[1][r] = __expf(sc[1][r] - mnew);
                    float rs = red_sum16(sc[0][r] + sc[1][r]);
                    lrow[r] = lrow[r] * alpha[r] + rs;
                }
#pragma unroll
                for (int dt = 0; dt < 8; ++dt)
#pragma unroll
                    for (int r = 0; r < 4; ++r) oacc[dt][r] *= alpha[r];

                // P -> bf16 -> wave-private swizzled LDS (1KB/wave) -> A-frag
#pragma unroll
                for (int nt = 0; nt < 2; ++nt)
#pragma unroll
                    for (int r = 0; r < 4; ++r) {
                        int row = quad * 4 + r;
                        int col = nt * 16 + lo16;
                        *(ushort_t*)(Pw + row * 64 + (((col >> 3) ^ (row & 3)) << 4) + (col & 7) * 2)
                            = f2bf(sc[nt][r]);
                    }
                bf16x8 pf = *(const bf16x8*)(Pw + lo16 * 64 + (quad ^ (lo16 & 3)) * 16);

                // O += P.V
                __builtin_amdgcn_s_setprio(1);
#pragma unroll
                for (int dt = 0; dt < 8; ++dt) {
                    int phys = quad ^ (lo16 & 3);
                    bf16x8 vb = *(const bf16x8*)(Vs + (dt * 16 + lo16) * 32 + phys * 8);
                    oacc[dt] = __builtin_amdgcn_mfma_f32_16x16x32_bf16(pf, vb, oacc[dt], 0, 0, 0);
                }
                __builtin_amdgcn_s_setprio(0);
            }
            buf ^= 1;
        }

        // ---- epilogue ----
#pragma unroll
        for (int r = 0; r < 4; ++r) {
            const float inv = 1.0f / lrow[r];
            const ll row = (ll)(b * 2048 + t0 + 16 * wl + quad * 4 + r);
#pragma unroll
            for (int dt = 0; dt < 8; ++dt)
                out[row * 2048 + h * 128 + dt * 16 + lo16] = oacc[dt][r] * inv;
        }
    }
}

// ---------------- rope kernels (depend on gemm outputs; stay separate) ----------------
// rope on XP cols [1024..1088) in place (bf16)
__global__ void rope_kr(ushort_t* __restrict__ XP, const float* __restrict__ cb,
                        const float* __restrict__ sb)
{
    int idx = blockIdx.x * 256 + threadIdx.x;   // 2*2048*32
    if (idx >= 2 * 2048 * 32) return;
    int j = idx & 31, t = (idx >> 5) & 2047, b = idx >> 16;
    float c = cb[t * 32 + j], s = sb[t * 32 + j];
    ushort_t* p = XP + ((ll)(b * 2048 + t)) * 1152 + 1024 + 2 * j;
    float re = bf2f(p[0]), im = bf2f(p[1]);
    p[0] = f2bf(re * c - im * s);
    p[1] = f2bf(re * s + im * c);
}

// rope on QP cols [2048..3072) in place (bf16)
__global__ void rope_qr_ip(ushort_t* __restrict__ QP, const float* __restrict__ cb,
                           const float* __restrict__ sb)
{
    int idx = blockIdx.x * 256 + threadIdx.x;   // 4096*512 pairs
    if (idx >= 4096 * 512) return;
    int pj = idx & 511, h = pj >> 5, j = pj & 31;
    int row = idx >> 9;
    int t = row & 2047;
    float c = cb[t * 32 + j], s = sb[t * 32 + j];
    ll base = (ll)row * 3072 + 2048 + h * 64 + 2 * j;
    float re = bf2f(QP[base]), im = bf2f(QP[base + 1]);
    QP[base]     = f2bf(re * c - im * s);
    QP[base + 1] = f2bf(re * s + im * c);
}

// ---------------- host ----------------
static inline void gemmb(hipStream_t st, const ushort_t* A, const ushort_t* B, void* C,
                         int M, int N, int K, int a_rs, int b_rs, int c_rs,
                         int nb, int Z2,
                         ll a_bs1, ll a_bs2, ll b_bs1, ll b_bs2, ll c_bs1, ll c_bs2,
                         int of32)
{
    dim3 g(N / TN, M / TM, nb);
    gemm_bf16<<<g, 256, 0, st>>>(A, B, C, M, N, K, a_rs, b_rs, c_rs, Z2,
                                 a_bs1, a_bs2, b_bs1, b_bs2, c_bs1, c_bs2, of32);
}

extern "C" void kernel_launch(void* const* d_in, const int* in_sizes, int n_in,
                              void* d_out, int out_size, void* d_ws, size_t ws_size,
                              hipStream_t stream)
{
    const float* x     = (const float*)d_in[0];
    const float* cosb  = (const float*)d_in[1];
    const float* sinb  = (const float*)d_in[2];
    const float* W_dq  = (const float*)d_in[3];
    const float* W_uq  = (const float*)d_in[4];
    const float* W_dkv = (const float*)d_in[5];
    const float* W_uk  = (const float*)d_in[6];
    const float* W_uv  = (const float*)d_in[7];
    const float* W_qr  = (const float*)d_in[8];
    const float* W_kr  = (const float*)d_in[9];
    const float* W_o   = (const float*)d_in[10];
    float* out = (float*)d_out;

    const float scale = 0.07216878364870323f; // 1/sqrt(128+64)

    // ---- workspace (bytes), total 90.7 MB ----
    char* base = (char*)d_ws;
    ushort_t* WB1     = (ushort_t*)(base + 0);         // [1152][2048]       4.72 MB
    ushort_t* WukT_b  = (ushort_t*)(base + 4718592);   // [16][512][128]     2.10
    ushort_t* WuvT_b  = (ushort_t*)(base + 6815744);   // [512][2048]        2.10
    ushort_t* WB2     = (ushort_t*)(base + 8912896);   // [3072][512]        3.15
    ushort_t* veffT_b = (ushort_t*)(base + 12058624);  // [16][128][512]     2.10
    ushort_t* Wo_b    = (ushort_t*)(base + 14155776);  // [2048][2048]       8.39
    ushort_t* xb      = (ushort_t*)(base + 22544384);  // [4096][2048]       16.78
    ushort_t* XP      = (ushort_t*)(base + 39321600);  // [4096][1152]       9.44
    ushort_t* VT_all  = (ushort_t*)(base + 48758784);  // [2][16][128][2048] 16.78
    ushort_t* QP      = (ushort_t*)(base + 65536000);  // [4096][3072]       25.17
    float*    VTscr   = (float*)(base + 48758784);     // veff split-K partials (overlay,
                                                       // 4x1048576 f32 = 16.78 MB, dead
                                                       // before VT gemm writes VT_all)

    // ---- prep: one fused launch for all 7 layout kernels ----
    prep_all<<<18176, 256, 0, stream>>>(x, W_o, W_dq, W_dkv, W_kr, W_uk, W_uv, W_uq,
                                        W_qr, xb, Wo_b, WB1, WukT_b, WuvT_b, WB2);

    // veffT[h][d][k] = sum_c Wo[h*128+d][c] * WuvT[k][c] — split-K x4 (256 blocks)
    // z = split*16 + head: A += split*512 + head*262144; B += split*512; C(f32 scratch)
    gemmb(stream, Wo_b, WuvT_b, VTscr, 128, 512, 512, 2048, 2048, 512,
          64, 16, 512, 262144, 512, 0, 1048576, 65536, 1);
    reduce_veff<<<1024, 256, 0, stream>>>(VTscr, veffT_b);

    // XP = xb . WB1^T  ->  [cq | c_kv | c_kr | pad]
    gemmb(stream, xb, WB1, XP, 4096, 1152, 2048, 2048, 2048, 1152,
          1, 1, 0, 0, 0, 0, 0, 0, 0);
    rope_kr<<<512, 256, 0, stream>>>(XP, cosb, sinb);

    // VT[b][h][d][s] = sum_k veffT[h][d][k] * c_kv[b][s][k]  (overwrites VTscr — dead)
    gemmb(stream, veffT_b, XP + 512, VT_all, 128, 2048, 512, 512, 1152, 2048,
          32, 16, 0, 65536, (ll)2048 * 1152, 0, (ll)16 * 262144, 262144, 0);

    // QP = cq . WB2^T  ->  [q_up | q_r]; rope q_r in place
    gemmb(stream, XP, WB2, QP, 4096, 3072, 512, 1152, 512, 3072,
          1, 1, 0, 0, 0, 0, 0, 0, 0);
    rope_qr_ip<<<8192, 256, 0, stream>>>(QP, cosb, sinb);

    // ---- fused attention: 256 blocks (bx in [0,8)), dbuf staging, 68 stages each ----
    flash_mla<<<dim3(8, 16, 2), 512, 0, stream>>>(QP, WukT_b, XP, VT_all, out, scale);

    (void)in_sizes; (void)n_in; (void)out_size; (void)ws_size;
}